// Round 1
// baseline (697.597 us; speedup 1.0000x reference)
//
#include <hip/hip_runtime.h>
#include <math.h>

// ---------------------------------------------------------------------------
// Swin-3D cross-attention block. Round 6: k_mlp software pipeline — hidden
// chunk 96, per-wave double-buffered h scratch, hand-unrolled s1/s2 overlap.
// Token order = window-partitioned:
//   win = ((b*8 + d/5)*8 + h/6)*8 + w/5 ; t = ((d%5)*6 + h%6)*5 + w%5
// Round 7: resubmission of the verified 700.1 µs kernel — previous bench run
// died with an infra-level container error (no counters); re-baselining.
// ---------------------------------------------------------------------------

static constexpr int NTOK = 153600;
static constexpr float SCALE = 0.10206207261596575f; // 96^-0.5

typedef __bf16 bf16_t;
typedef __bf16 bf16x8 __attribute__((ext_vector_type(8)));
typedef float f32x4 __attribute__((ext_vector_type(4)));

__device__ __forceinline__ int tok_index(int b, int d, int h, int w) {
    int d0 = d / 5, wd = d % 5;
    int h0 = h / 6, wh = h % 6;
    int w0 = w / 5, ww = w % 5;
    int win = ((b * 8 + d0) * 8 + h0) * 8 + w0;
    return win * 150 + (wd * 6 + wh) * 5 + ww;
}

__device__ __forceinline__ float gelu_f(float u) {
    float u2 = u * u;
    float arg = u * fmaf(0.0713549f, u2, 1.5957691f);
    float e = __expf(arg);
    float r = __builtin_amdgcn_rcpf(e + 1.f);
    return fmaf(-u, r, u);
}

// ---------------------------------------------------------------------------
// K0: weight convert/transpose bf16 [n][k]; fp32 bias matrix [160][160];
// conv weights re-laid to cwT[kk][oc][ci] (ci-contiguous for float4 reads).
// ---------------------------------------------------------------------------
__global__ __launch_bounds__(256) void k_prep_weights(
    const float* __restrict__ wq, const float* __restrict__ wkv,
    const float* __restrict__ w1, const float* __restrict__ w2,
    const float* __restrict__ wproj, const float* __restrict__ relb,
    const float* __restrict__ cw,
    bf16_t* wqT, bf16_t* wkvT, bf16_t* w1T, bf16_t* w2T, bf16_t* wpjT,
    float* bias_mat, float* cwT)
{
    int i = blockIdx.x * 256 + threadIdx.x;
    if (i < 9216)  wqT[i]  = (bf16_t)wq[(i % 96) * 96 + i / 96];
    if (i < 18432) wkvT[i] = (bf16_t)wkv[(i % 96) * 192 + i / 96];
    if (i < 36864) w1T[i]  = (bf16_t)w1[(i % 96) * 384 + i / 96];
    if (i < 36864) w2T[i]  = (bf16_t)w2[(i % 384) * 96 + i / 384];
    if (i < 9216)  wpjT[i] = (bf16_t)wproj[(i % 96) * 96 + i / 96];
    if (i < 25600) {
        int row = i / 160, col = i % 160;
        float v;
        if (col >= 150) v = -1e30f;
        else if (row >= 150) v = 0.f;
        else {
            int wd1 = row / 30, rh1 = row % 30, wh1 = rh1 / 5, ww1 = rh1 % 5;
            int wd2 = col / 30, rh2 = col % 30, wh2 = rh2 / 5, ww2 = rh2 % 5;
            int idx = (wd1 - wd2 + 4) * 99 + (wh1 - wh2 + 5) * 9 + (ww1 - ww2 + 4);
            v = relb[idx];
        }
        bias_mat[i] = v;
    }
    if (i < 7776) {
        int kk = i / 288, rem = i % 288;
        int oc = rem / 96, ci = rem % 96;
        cwT[i] = cw[oc * 2592 + ci * 27 + kk];
    }
}

// ---------------------------------------------------------------------------
// K1: transpose->token order + LayerNorm (bf16 out) + fp32 Im shortcut to x2.
// grid = 3840, 256 threads.
// ---------------------------------------------------------------------------
__global__ __launch_bounds__(256) void k_ln_transpose(
    const float* __restrict__ Im, const float* __restrict__ If,
    const float* __restrict__ g1q, const float* __restrict__ b1q,
    const float* __restrict__ g1k, const float* __restrict__ b1k,
    bf16_t* __restrict__ xln, bf16_t* __restrict__ yln,
    float* __restrict__ x2s)
{
    __shared__ float tile[40 * 97];
    __shared__ float mean_s[40], rstd_s[40];
    int blk = blockIdx.x;
    int b = blk / (40 * 48);
    int rem = blk % (40 * 48);
    int d = rem / 48, h = rem % 48;
    int tid = threadIdx.x;

    for (int pass = 0; pass < 2; ++pass) {
        const float* src = pass ? If : Im;
        const float* gg = pass ? g1k : g1q;
        const float* bb = pass ? b1k : b1q;
        bf16_t* dst = pass ? yln : xln;

        for (int i = tid; i < 96 * 40; i += 256) {
            int c = i / 40, w = i % 40;
            tile[w * 97 + c] = src[(size_t)(b * 96 + c) * 76800 + d * 1920 + h * 40 + w];
        }
        __syncthreads();
        if (tid < 40) {
            float s = 0.f, s2 = 0.f;
            for (int c = 0; c < 96; ++c) {
                float v = tile[tid * 97 + c];
                s += v; s2 += v * v;
            }
            float m = s * (1.f / 96.f);
            float var = s2 * (1.f / 96.f) - m * m;
            mean_s[tid] = m;
            rstd_s[tid] = rsqrtf(var + 1e-5f);
        }
        __syncthreads();
        for (int i = tid; i < 40 * 96; i += 256) {
            int w = i / 96, c = i % 96;
            int tok = tok_index(b, d, h, w);
            float raw = tile[w * 97 + c];
            float v = (raw - mean_s[w]) * rstd_s[w] * gg[c] + bb[c];
            dst[(size_t)tok * 96 + c] = (bf16_t)v;
            if (pass == 0) x2s[(size_t)tok * 96 + c] = raw;   // shortcut
        }
        __syncthreads();
    }
}

// ---------------------------------------------------------------------------
// K2: MFMA projection. WT is [N][96] bf16. N=96 -> qb only.
// N=192 -> n<96 writes kb [t][c]; n>=96 writes vT [win][c][160].
// grid = 2400 (64 tokens/block), 256 threads = 4 waves.
// ---------------------------------------------------------------------------
__global__ __launch_bounds__(256) void k_proj_mfma(
    const bf16_t* __restrict__ X, const bf16_t* __restrict__ WT,
    const float* __restrict__ bias, int N,
    bf16_t* __restrict__ outA, bf16_t* __restrict__ vT)
{
    __shared__ bf16_t xs[64 * 104];
    int tid = threadIdx.x;
    int t0 = blockIdx.x * 64;

    const uint4* xg = (const uint4*)(X + (size_t)t0 * 96);
    uint4* xsv = (uint4*)xs;
    for (int i = tid; i < 768; i += 256) {
        int row = i / 12, c16 = i % 12;
        xsv[row * 13 + c16] = xg[i];
    }
    __syncthreads();

    int w = tid >> 6, l = tid & 63;
    int lm = l & 15, lk = (l >> 4) * 8;
    int m0 = w * 16;
    bf16x8 a[3];
#pragma unroll
    for (int kk = 0; kk < 3; ++kk)
        a[kk] = *(const bf16x8*)(xs + (m0 + lm) * 104 + kk * 32 + lk);

    int trow[4], twin[4], tm[4];
#pragma unroll
    for (int r = 0; r < 4; ++r) {
        int t = t0 + m0 + (l >> 4) * 4 + r;
        trow[r] = t; twin[r] = t / 150; tm[r] = t - twin[r] * 150;
    }

    int ntiles = N >> 4;
    for (int ti = 0; ti < ntiles; ++ti) {
        int n0 = ti * 16;
        f32x4 c = {0.f, 0.f, 0.f, 0.f};
        const bf16_t* wp = WT + (size_t)(n0 + lm) * 96 + lk;
        c = __builtin_amdgcn_mfma_f32_16x16x32_bf16(a[0], *(const bf16x8*)(wp), c, 0, 0, 0);
        c = __builtin_amdgcn_mfma_f32_16x16x32_bf16(a[1], *(const bf16x8*)(wp + 32), c, 0, 0, 0);
        c = __builtin_amdgcn_mfma_f32_16x16x32_bf16(a[2], *(const bf16x8*)(wp + 64), c, 0, 0, 0);
        int n = n0 + lm;
        float bs = bias[n];
        if (n < 96) {
#pragma unroll
            for (int r = 0; r < 4; ++r)
                outA[(size_t)trow[r] * 96 + n] = (bf16_t)(c[r] + bs);
        } else {
            int cc = n - 96;
#pragma unroll
            for (int r = 0; r < 4; ++r)
                vT[((size_t)twin[r] * 96 + cc) * 160 + tm[r]] = (bf16_t)(c[r] + bs);
        }
    }
}

// ---------------------------------------------------------------------------
// K34: MFMA attention, one block (6 waves) per window. K staged in LDS once
// ([160][104] bf16, rows>=150 zeroed); each wave owns row-tiles wv, wv+6.
// P/O round-trip through per-wave LDS scratch [16][164]. V and wproj B-frags
// straight from global (L2-hot). x2 += O@wprojT + bproj (shortcut pre-added).
// ---------------------------------------------------------------------------
__global__ __launch_bounds__(384) void k_attn_mfma(
    const bf16_t* __restrict__ qb, const bf16_t* __restrict__ kb,
    const bf16_t* __restrict__ vT, const bf16_t* __restrict__ wpjT,
    const float* __restrict__ bias_mat, const float* __restrict__ bproj,
    float* __restrict__ x2)
{
    __shared__ __align__(16) bf16_t kls[160 * 104];        // 33280 B
    __shared__ __align__(16) bf16_t pls_all[6 * 16 * 164]; // 31488 B
    int win = blockIdx.x;
    int tid = threadIdx.x;
    int wv = tid >> 6, l = tid & 63;
    int lm = l & 15, lq = l >> 4, lk8 = lq * 8;
    size_t wbase = (size_t)win * 150 * 96;
    size_t vbase = (size_t)win * 96 * 160;
    bf16_t* pls = pls_all + wv * 16 * 164;

    // ---- stage K into LDS (coalesced 16B chunks), zero pad rows 150..159 ----
    {
        const uint4* src = (const uint4*)(kb + wbase);   // 150 rows x 12 chunks
        for (int i = tid; i < 1800; i += 384) {
            int row = i / 12, c = i % 12;
            *(uint4*)(kls + row * 104 + c * 8) = src[i];
        }
        uint4 z = {0, 0, 0, 0};
        for (int i = tid; i < 130; i += 384) {           // 10 rows x 13 chunks
            int row = 150 + i / 13, c = i % 13;
            *(uint4*)(kls + row * 104 + c * 8) = z;
        }
    }
    __syncthreads();

    for (int ti = wv; ti < 10; ti += 6) {
        int r0 = ti * 16;

        // ---- S = Q K^T (Q A-frags from global, K B-frags from LDS) ----
        bf16x8 aq[3];
#pragma unroll
        for (int kk = 0; kk < 3; ++kk)
            aq[kk] = *(const bf16x8*)(qb + wbase + (size_t)(r0 + lm) * 96 + kk * 32 + lk8);

        f32x4 s[10];
#pragma unroll
        for (int nt = 0; nt < 10; ++nt) {
            f32x4 acc = {0.f, 0.f, 0.f, 0.f};
            const bf16_t* kp = kls + (nt * 16 + lm) * 104 + lk8;
            acc = __builtin_amdgcn_mfma_f32_16x16x32_bf16(aq[0], *(const bf16x8*)(kp), acc, 0, 0, 0);
            acc = __builtin_amdgcn_mfma_f32_16x16x32_bf16(aq[1], *(const bf16x8*)(kp + 32), acc, 0, 0, 0);
            acc = __builtin_amdgcn_mfma_f32_16x16x32_bf16(aq[2], *(const bf16x8*)(kp + 64), acc, 0, 0, 0);
            s[nt] = acc;
        }

        // ---- softmax (bias+mask folded into bias_mat) ----
#pragma unroll
        for (int r = 0; r < 4; ++r) {
            int grow = r0 + lq * 4 + r;
            float rowmax = -3.0e38f;
#pragma unroll
            for (int nt = 0; nt < 10; ++nt) {
                float bv = bias_mat[grow * 160 + nt * 16 + lm];
                float v = fmaf(s[nt][r], SCALE, bv);
                s[nt][r] = v;
                rowmax = fmaxf(rowmax, v);
            }
            rowmax = fmaxf(rowmax, __shfl_xor(rowmax, 1));
            rowmax = fmaxf(rowmax, __shfl_xor(rowmax, 2));
            rowmax = fmaxf(rowmax, __shfl_xor(rowmax, 4));
            rowmax = fmaxf(rowmax, __shfl_xor(rowmax, 8));
            float ssum = 0.f;
#pragma unroll
            for (int nt = 0; nt < 10; ++nt) {
                float e = __expf(s[nt][r] - rowmax);
                s[nt][r] = e;
                ssum += e;
            }
            ssum += __shfl_xor(ssum, 1);
            ssum += __shfl_xor(ssum, 2);
            ssum += __shfl_xor(ssum, 4);
            ssum += __shfl_xor(ssum, 8);
            float inv = 1.f / ssum;
            int lrow = lq * 4 + r;
#pragma unroll
            for (int nt = 0; nt < 10; ++nt)
                pls[lrow * 164 + nt * 16 + lm] = (bf16_t)(s[nt][r] * inv);
        }
        // wave-private LDS: no barrier needed (lgkmcnt orders within wave)

        // ---- O = P @ V (P A-frags from LDS, V B-frags from global) ----
        f32x4 o[6];
#pragma unroll
        for (int ct = 0; ct < 6; ++ct) o[ct] = (f32x4){0.f, 0.f, 0.f, 0.f};
#pragma unroll
        for (int kf = 0; kf < 5; ++kf) {
            bf16x8 ap = *(const bf16x8*)(pls + lm * 164 + kf * 32 + lk8);
#pragma unroll
            for (int ct = 0; ct < 6; ++ct) {
                const bf16_t* vp = vT + vbase + (size_t)(ct * 16 + lm) * 160 + kf * 32 + lk8;
                o[ct] = __builtin_amdgcn_mfma_f32_16x16x32_bf16(ap, *(const bf16x8*)(vp), o[ct], 0, 0, 0);
            }
        }

        // ---- O -> LDS (A-layout staging), reuse pls as [16][104] ----
#pragma unroll
        for (int ct = 0; ct < 6; ++ct)
#pragma unroll
            for (int r = 0; r < 4; ++r)
                pls[(lq * 4 + r) * 104 + ct * 16 + lm] = (bf16_t)o[ct][r];

        // ---- x2 += O @ wprojT + bproj ----
        bf16x8 ao[3];
#pragma unroll
        for (int kk = 0; kk < 3; ++kk)
            ao[kk] = *(const bf16x8*)(pls + lm * 104 + kk * 32 + lk8);
        f32x4 pj[6];
#pragma unroll
        for (int ct = 0; ct < 6; ++ct) {
            f32x4 acc = {0.f, 0.f, 0.f, 0.f};
            const bf16_t* wp = wpjT + (size_t)(ct * 16 + lm) * 96 + lk8;
            acc = __builtin_amdgcn_mfma_f32_16x16x32_bf16(ao[0], *(const bf16x8*)(wp), acc, 0, 0, 0);
            acc = __builtin_amdgcn_mfma_f32_16x16x32_bf16(ao[1], *(const bf16x8*)(wp + 32), acc, 0, 0, 0);
            acc = __builtin_amdgcn_mfma_f32_16x16x32_bf16(ao[2], *(const bf16x8*)(wp + 64), acc, 0, 0, 0);
            pj[ct] = acc;
        }
#pragma unroll
        for (int r = 0; r < 4; ++r) {
            int gr = r0 + lq * 4 + r;
            if (gr < 150) {
                size_t t = (size_t)win * 150 + gr;
#pragma unroll
                for (int ct = 0; ct < 6; ++ct) {
                    int c = ct * 16 + lm;
                    size_t off = t * 96 + c;
                    x2[off] = x2[off] + pj[ct][r] + bproj[c];
                }
            }
        }
    }
}

// ---------------------------------------------------------------------------
// K5: MFMA MLP, software-pipelined. LN in registers; hidden in 4 chunks of 96
// with per-wave DOUBLE-BUFFERED h scratch so stage1(cc+1) overlaps stage2(cc).
// LDS = 13312 (xs) + 4*2*3328 (hs dbuf) = 39936 B -> 4 blocks/CU.
// x3 = x2 + gelu(ln2(x2)@w1+b1)@w2+b2, written bf16 in SPATIAL order for conv.
// grid = 2400 (64 tokens), 256 threads = 4 waves.
// ---------------------------------------------------------------------------
__global__ __launch_bounds__(256, 4) void k_mlp_mfma(
    const float* __restrict__ x2,
    const float* __restrict__ g2, const float* __restrict__ b2,
    const bf16_t* __restrict__ w1T, const float* __restrict__ b1,
    const bf16_t* __restrict__ w2T, const float* __restrict__ b2v,
    bf16_t* __restrict__ xc)
{
    __shared__ __align__(16) bf16_t xs[64 * 104];          // 13312 B
    __shared__ __align__(16) bf16_t hs[4 * 2 * 16 * 104];  // 26624 B

    int tid = threadIdx.x;
    int t0 = blockIdx.x * 64;

    // ---- register LayerNorm: thread = (token t, quarter p) ----
    {
        int t = tid >> 2, p = tid & 3;
        float xr[24];
        const float4* xg = (const float4*)(x2 + (size_t)(t0 + t) * 96 + p * 24);
#pragma unroll
        for (int j4 = 0; j4 < 6; ++j4) {
            float4 v = xg[j4];
            xr[j4 * 4 + 0] = v.x; xr[j4 * 4 + 1] = v.y;
            xr[j4 * 4 + 2] = v.z; xr[j4 * 4 + 3] = v.w;
        }
        float s = 0.f, s2 = 0.f;
#pragma unroll
        for (int j = 0; j < 24; ++j) { s += xr[j]; s2 += xr[j] * xr[j]; }
        s += __shfl_xor(s, 1); s += __shfl_xor(s, 2);
        s2 += __shfl_xor(s2, 1); s2 += __shfl_xor(s2, 2);
        float m = s * (1.f / 96.f);
        float var = s2 * (1.f / 96.f) - m * m;
        float rstd = rsqrtf(var + 1e-5f);

        const float4* gg = (const float4*)(g2 + p * 24);
        const float4* bb = (const float4*)(b2 + p * 24);
        bf16_t tmp[24];
#pragma unroll
        for (int j4 = 0; j4 < 6; ++j4) {
            float4 g = gg[j4], bv = bb[j4];
            tmp[j4 * 4 + 0] = (bf16_t)((xr[j4 * 4 + 0] - m) * rstd * g.x + bv.x);
            tmp[j4 * 4 + 1] = (bf16_t)((xr[j4 * 4 + 1] - m) * rstd * g.y + bv.y);
            tmp[j4 * 4 + 2] = (bf16_t)((xr[j4 * 4 + 2] - m) * rstd * g.z + bv.z);
            tmp[j4 * 4 + 3] = (bf16_t)((xr[j4 * 4 + 3] - m) * rstd * g.w + bv.w);
        }
        uint4* dst = (uint4*)(xs + t * 104 + p * 24);   // 48B per quarter
        const uint4* src = (const uint4*)tmp;
        dst[0] = src[0]; dst[1] = src[1]; dst[2] = src[2];
    }
    __syncthreads();

    int w = tid >> 6, l = tid & 63;
    int lm = l & 15, lk = (l >> 4) * 8;
    int m0 = w * 16;
    bf16_t* hw0 = hs + w * 2 * 16 * 104;   // buffer 0
    bf16_t* hw1 = hw0 + 16 * 104;          // buffer 1

    bf16x8 a[3];
#pragma unroll
    for (int kk = 0; kk < 3; ++kk)
        a[kk] = *(const bf16x8*)(xs + (m0 + lm) * 104 + kk * 32 + lk);

    // stage1 of chunk cc into given buffer: h = gelu(xs @ w1_chunk + b1)
    auto s1 = [&](int cc, bf16_t* buf) {
#pragma unroll
        for (int ti = 0; ti < 6; ++ti) {
            int n = cc * 96 + ti * 16 + lm;
            const bf16_t* wp = w1T + (size_t)n * 96 + lk;
            f32x4 c1 = {0.f, 0.f, 0.f, 0.f};
            c1 = __builtin_amdgcn_mfma_f32_16x16x32_bf16(a[0], *(const bf16x8*)(wp), c1, 0, 0, 0);
            c1 = __builtin_amdgcn_mfma_f32_16x16x32_bf16(a[1], *(const bf16x8*)(wp + 32), c1, 0, 0, 0);
            c1 = __builtin_amdgcn_mfma_f32_16x16x32_bf16(a[2], *(const bf16x8*)(wp + 64), c1, 0, 0, 0);
            float bs = b1[n];
#pragma unroll
            for (int r = 0; r < 4; ++r) {
                int row = (l >> 4) * 4 + r;
                buf[row * 104 + ti * 16 + lm] = (bf16_t)gelu_f(c1[r] + bs);
            }
        }
    };

    f32x4 acc2[6];
#pragma unroll
    for (int i = 0; i < 6; ++i) acc2[i] = (f32x4){0.f, 0.f, 0.f, 0.f};

    bf16x8 ha[3];
    // ---- software pipeline: s1(0); rd(0); { s1(cc+1) | s2(cc) | rd(cc+1) } --
    s1(0, hw0);
#pragma unroll
    for (int kk = 0; kk < 3; ++kk)
        ha[kk] = *(const bf16x8*)(hw0 + lm * 104 + kk * 32 + lk);

#pragma unroll
    for (int cc = 0; cc < 4; ++cc) {
        bf16_t* nbuf = (cc & 1) ? hw0 : hw1;
        if (cc < 3) s1(cc + 1, nbuf);          // independent of ha -> overlaps
        // stage2: acc2 += h_chunk @ w2_chunk
#pragma unroll
        for (int ti = 0; ti < 6; ++ti) {
            const bf16_t* wp = w2T + (size_t)(ti * 16 + lm) * 384 + cc * 96 + lk;
#pragma unroll
            for (int kk = 0; kk < 3; ++kk)
                acc2[ti] = __builtin_amdgcn_mfma_f32_16x16x32_bf16(
                    ha[kk], *(const bf16x8*)(wp + kk * 32), acc2[ti], 0, 0, 0);
        }
        if (cc < 3) {
#pragma unroll
            for (int kk = 0; kk < 3; ++kk)
                ha[kk] = *(const bf16x8*)(nbuf + lm * 104 + kk * 32 + lk);
        }
    }

    // epilogue: residual + bias; write bf16 in spatial order for the conv
    int srow[4];
#pragma unroll
    for (int r = 0; r < 4; ++r) {
        int t = t0 + m0 + (l >> 4) * 4 + r;
        int win = t / 150, nn = t - win * 150;
        int b = win >> 9, d0 = (win >> 6) & 7, h0 = (win >> 3) & 7, w0 = win & 7;
        int wd = nn / 30, rem = nn % 30, wh = rem / 5, ww = rem % 5;
        srow[r] = ((b * 40 + d0 * 5 + wd) * 48 + h0 * 6 + wh) * 40 + w0 * 5 + ww;
    }
#pragma unroll
    for (int ti = 0; ti < 6; ++ti) {
        int n = ti * 16 + lm;
        float bs = b2v[n];
#pragma unroll
        for (int r = 0; r < 4; ++r) {
            int t = t0 + m0 + (l >> 4) * 4 + r;
            size_t o = (size_t)t * 96 + n;
            xc[(size_t)srow[r] * 96 + n] = (bf16_t)(x2[o] + acc2[ti][r] + bs);
        }
    }
}

// ---------------------------------------------------------------------------
// K6: 3x3x3 conv (96 -> 3), zero pad. Input xc: bf16, spatial (b,d,h,w,c).
// Weights cwT[kk][oc][ci] staged in LDS, read as broadcast float4.
// grid = 600, 256 threads (one thread per spatial point, 3 out channels).
// ---------------------------------------------------------------------------
__global__ __launch_bounds__(256) void k_conv(
    const bf16_t* __restrict__ xc, const float* __restrict__ cwT,
    const float* __restrict__ cb, float* __restrict__ out)
{
    __shared__ float wl[7776];   // [kk][oc][ci]
    int tid = threadIdx.x;
    for (int i = tid; i < 7776; i += 256) wl[i] = cwT[i];
    __syncthreads();

    int s = blockIdx.x * 256 + tid;
    int b = s / 76800, r = s % 76800;
    int d = r / 1920, h = (r / 40) % 48, w = r % 40;
    float a0 = 0.f, a1 = 0.f, a2 = 0.f;

    for (int dd = 0; dd < 3; ++dd) {
        int d2 = d + dd - 1;
        if ((unsigned)d2 >= 40u) continue;
        for (int hh = 0; hh < 3; ++hh) {
            int h2 = h + hh - 1;
            if ((unsigned)h2 >= 48u) continue;
            for (int ww = 0; ww < 3; ++ww) {
                int w2 = w + ww - 1;
                if ((unsigned)w2 >= 40u) continue;
                int kk = (dd * 3 + hh) * 3 + ww;
                const bf16x8* xp = (const bf16x8*)
                    (xc + ((size_t)((b * 40 + d2) * 48 + h2) * 40 + w2) * 96);
                const float* wk = wl + kk * 288;
#pragma unroll
                for (int c8 = 0; c8 < 12; ++c8) {
                    bf16x8 xv = xp[c8];
                    float x0 = (float)xv[0], x1 = (float)xv[1];
                    float x2v = (float)xv[2], x3 = (float)xv[3];
                    float x4 = (float)xv[4], x5 = (float)xv[5];
                    float x6 = (float)xv[6], x7 = (float)xv[7];
                    float4 wa0 = *(const float4*)(wk + c8 * 8);
                    float4 wb0 = *(const float4*)(wk + c8 * 8 + 4);
                    float4 wa1 = *(const float4*)(wk + 96 + c8 * 8);
                    float4 wb1 = *(const float4*)(wk + 96 + c8 * 8 + 4);
                    float4 wa2 = *(const float4*)(wk + 192 + c8 * 8);
                    float4 wb2 = *(const float4*)(wk + 192 + c8 * 8 + 4);
                    a0 += x0 * wa0.x + x1 * wa0.y + x2v * wa0.z + x3 * wa0.w
                        + x4 * wb0.x + x5 * wb0.y + x6 * wb0.z + x7 * wb0.w;
                    a1 += x0 * wa1.x + x1 * wa1.y + x2v * wa1.z + x3 * wa1.w
                        + x4 * wb1.x + x5 * wb1.y + x6 * wb1.z + x7 * wb1.w;
                    a2 += x0 * wa2.x + x1 * wa2.y + x2v * wa2.z + x3 * wa2.w
                        + x4 * wb2.x + x5 * wb2.y + x6 * wb2.z + x7 * wb2.w;
                }
            }
        }
    }
    out[(size_t)(b * 3 + 0) * 76800 + r] = a0 + cb[0];
    out[(size_t)(b * 3 + 1) * 76800 + r] = a1 + cb[1];
    out[(size_t)(b * 3 + 2) * 76800 + r] = a2 + cb[2];
}

// ---------------------------------------------------------------------------
extern "C" void kernel_launch(void* const* d_in, const int* in_sizes, int n_in,
                              void* d_out, int out_size, void* d_ws, size_t ws_size,
                              hipStream_t stream)
{
    (void)in_sizes; (void)n_in; (void)out_size;

    const float* Im  = (const float*)d_in[0];
    const float* If  = (const float*)d_in[1];
    const float* g1q = (const float*)d_in[2];
    const float* b1q = (const float*)d_in[3];
    const float* g1k = (const float*)d_in[4];
    const float* b1k = (const float*)d_in[5];
    const float* wq  = (const float*)d_in[6];
    const float* bq  = (const float*)d_in[7];
    const float* wkv = (const float*)d_in[8];
    const float* bkv = (const float*)d_in[9];
    const float* wpj = (const float*)d_in[10];
    const float* bpj = (const float*)d_in[11];
    const float* rb  = (const float*)d_in[12];
    const float* g2  = (const float*)d_in[13];
    const float* b2  = (const float*)d_in[14];
    const float* w1  = (const float*)d_in[15];
    const float* b1  = (const float*)d_in[16];
    const float* w2  = (const float*)d_in[17];
    const float* b2v = (const float*)d_in[18];
    const float* cw  = (const float*)d_in[19];
    const float* cb  = (const float*)d_in[20];
    float* out = (float*)d_out;

    size_t U = (size_t)NTOK * 96;
    if (ws_size < 4 * U * sizeof(float)) return;
    float* ws = (float*)d_ws;
    bf16_t* xlnb = (bf16_t*)ws;                        // U bf16 (-> xc later)
    bf16_t* ylnb = (bf16_t*)(ws + U / 2);              // U bf16
    bf16_t* qb   = (bf16_t*)(ws + U);                  // U bf16
    bf16_t* kb   = (bf16_t*)(ws + 3 * U / 2);          // U bf16
    bf16_t* vT   = (bf16_t*)(ws + 2 * U);              // 1024*96*160 bf16
    float*  wtail = ws + 2 * U + (1024 * 96 * 160) / 2;
    bf16_t* wqT  = (bf16_t*)wtail;                     // 9216
    bf16_t* wkvT = wqT + 9216;                         // 18432
    bf16_t* w1T  = wkvT + 18432;                       // 36864
    bf16_t* w2T  = w1T + 36864;                        // 36864
    bf16_t* wpjT = w2T + 36864;                        // 9216
    float*  bias_mat = (float*)(wpjT + 9216 + 2);      // 25600 fp32
    float*  cwT  = bias_mat + 25600;                   // 7776 fp32
    float*  x2f  = ws + 3 * U;                         // U fp32
    bf16_t* xc   = (bf16_t*)ws;                        // U bf16, spatial order

    k_prep_weights<<<144, 256, 0, stream>>>(wq, wkv, w1, w2, wpj, rb, cw,
                                            wqT, wkvT, w1T, w2T, wpjT,
                                            bias_mat, cwT);
    k_ln_transpose<<<3840, 256, 0, stream>>>(Im, If, g1q, b1q, g1k, b1k,
                                             xlnb, ylnb, x2f);
    k_proj_mfma<<<2400, 256, 0, stream>>>(xlnb, wqT, bq, 96, qb, nullptr);
    k_proj_mfma<<<2400, 256, 0, stream>>>(ylnb, wkvT, bkv, 192, kb, vT);
    k_attn_mfma<<<1024, 384, 0, stream>>>(qb, kb, vT, wpjT, bias_mat, bpj, x2f);
    k_mlp_mfma<<<2400, 256, 0, stream>>>(x2f, g2, b2, w1T, b1, w2T, b2v, xc);
    k_conv<<<600, 256, 0, stream>>>(xc, cwT, cb, out);
}

// Round 2
// 682.950 us; speedup vs baseline: 1.0214x; 1.0214x over previous
//
#include <hip/hip_runtime.h>
#include <math.h>

// ---------------------------------------------------------------------------
// Swin-3D cross-attention block. Round 8:
//  - k_mlp rewritten: latency-bound per counters (MfmaUtil 6%, VALU 19%,
//    580 GB/s, occ 38%). Single-buffered h scratch (LDS 39936->26624 B),
//    launch_bounds(256,5), explicit 3-tile register lookahead on w1/w2
//    B-frag loads, no post-LN barrier (xs is wave-private).
//  - k_proj: WT staged once per block into dynamic LDS (B-frags were
//    per-MFMA global loads = same latency disease).
// Token order = window-partitioned:
//   win = ((b*8 + d/5)*8 + h/6)*8 + w/5 ; t = ((d%5)*6 + h%6)*5 + w%5
// ---------------------------------------------------------------------------

static constexpr int NTOK = 153600;
static constexpr float SCALE = 0.10206207261596575f; // 96^-0.5

typedef __bf16 bf16_t;
typedef __bf16 bf16x8 __attribute__((ext_vector_type(8)));
typedef float f32x4 __attribute__((ext_vector_type(4)));

__device__ __forceinline__ int tok_index(int b, int d, int h, int w) {
    int d0 = d / 5, wd = d % 5;
    int h0 = h / 6, wh = h % 6;
    int w0 = w / 5, ww = w % 5;
    int win = ((b * 8 + d0) * 8 + h0) * 8 + w0;
    return win * 150 + (wd * 6 + wh) * 5 + ww;
}

__device__ __forceinline__ float gelu_f(float u) {
    float u2 = u * u;
    float arg = u * fmaf(0.0713549f, u2, 1.5957691f);
    float e = __expf(arg);
    float r = __builtin_amdgcn_rcpf(e + 1.f);
    return fmaf(-u, r, u);
}

// ---------------------------------------------------------------------------
// K0: weight convert/transpose bf16 [n][k]; fp32 bias matrix [160][160];
// conv weights re-laid to cwT[kk][oc][ci] (ci-contiguous for float4 reads).
// ---------------------------------------------------------------------------
__global__ __launch_bounds__(256) void k_prep_weights(
    const float* __restrict__ wq, const float* __restrict__ wkv,
    const float* __restrict__ w1, const float* __restrict__ w2,
    const float* __restrict__ wproj, const float* __restrict__ relb,
    const float* __restrict__ cw,
    bf16_t* wqT, bf16_t* wkvT, bf16_t* w1T, bf16_t* w2T, bf16_t* wpjT,
    float* bias_mat, float* cwT)
{
    int i = blockIdx.x * 256 + threadIdx.x;
    if (i < 9216)  wqT[i]  = (bf16_t)wq[(i % 96) * 96 + i / 96];
    if (i < 18432) wkvT[i] = (bf16_t)wkv[(i % 96) * 192 + i / 96];
    if (i < 36864) w1T[i]  = (bf16_t)w1[(i % 96) * 384 + i / 96];
    if (i < 36864) w2T[i]  = (bf16_t)w2[(i % 384) * 96 + i / 384];
    if (i < 9216)  wpjT[i] = (bf16_t)wproj[(i % 96) * 96 + i / 96];
    if (i < 25600) {
        int row = i / 160, col = i % 160;
        float v;
        if (col >= 150) v = -1e30f;
        else if (row >= 150) v = 0.f;
        else {
            int wd1 = row / 30, rh1 = row % 30, wh1 = rh1 / 5, ww1 = rh1 % 5;
            int wd2 = col / 30, rh2 = col % 30, wh2 = rh2 / 5, ww2 = rh2 % 5;
            int idx = (wd1 - wd2 + 4) * 99 + (wh1 - wh2 + 5) * 9 + (ww1 - ww2 + 4);
            v = relb[idx];
        }
        bias_mat[i] = v;
    }
    if (i < 7776) {
        int kk = i / 288, rem = i % 288;
        int oc = rem / 96, ci = rem % 96;
        cwT[i] = cw[oc * 2592 + ci * 27 + kk];
    }
}

// ---------------------------------------------------------------------------
// K1: transpose->token order + LayerNorm (bf16 out) + fp32 Im shortcut to x2.
// grid = 3840, 256 threads.
// ---------------------------------------------------------------------------
__global__ __launch_bounds__(256) void k_ln_transpose(
    const float* __restrict__ Im, const float* __restrict__ If,
    const float* __restrict__ g1q, const float* __restrict__ b1q,
    const float* __restrict__ g1k, const float* __restrict__ b1k,
    bf16_t* __restrict__ xln, bf16_t* __restrict__ yln,
    float* __restrict__ x2s)
{
    __shared__ float tile[40 * 97];
    __shared__ float mean_s[40], rstd_s[40];
    int blk = blockIdx.x;
    int b = blk / (40 * 48);
    int rem = blk % (40 * 48);
    int d = rem / 48, h = rem % 48;
    int tid = threadIdx.x;

    for (int pass = 0; pass < 2; ++pass) {
        const float* src = pass ? If : Im;
        const float* gg = pass ? g1k : g1q;
        const float* bb = pass ? b1k : b1q;
        bf16_t* dst = pass ? yln : xln;

        for (int i = tid; i < 96 * 40; i += 256) {
            int c = i / 40, w = i % 40;
            tile[w * 97 + c] = src[(size_t)(b * 96 + c) * 76800 + d * 1920 + h * 40 + w];
        }
        __syncthreads();
        if (tid < 40) {
            float s = 0.f, s2 = 0.f;
            for (int c = 0; c < 96; ++c) {
                float v = tile[tid * 97 + c];
                s += v; s2 += v * v;
            }
            float m = s * (1.f / 96.f);
            float var = s2 * (1.f / 96.f) - m * m;
            mean_s[tid] = m;
            rstd_s[tid] = rsqrtf(var + 1e-5f);
        }
        __syncthreads();
        for (int i = tid; i < 40 * 96; i += 256) {
            int w = i / 96, c = i % 96;
            int tok = tok_index(b, d, h, w);
            float raw = tile[w * 97 + c];
            float v = (raw - mean_s[w]) * rstd_s[w] * gg[c] + bb[c];
            dst[(size_t)tok * 96 + c] = (bf16_t)v;
            if (pass == 0) x2s[(size_t)tok * 96 + c] = raw;   // shortcut
        }
        __syncthreads();
    }
}

// ---------------------------------------------------------------------------
// K2: MFMA projection. WT is [N][96] bf16, staged once per block into LDS
// ([N][104] padded) so B-frags come from LDS, not per-MFMA global loads.
// N=96 -> qb only. N=192 -> n<96 writes kb [t][c]; n>=96 writes vT.
// grid = 2400 (64 tokens/block), 256 threads = 4 waves.
// dynamic LDS = (64*104 + N*104)*2 B.
// ---------------------------------------------------------------------------
__global__ __launch_bounds__(256) void k_proj_mfma(
    const bf16_t* __restrict__ X, const bf16_t* __restrict__ WT,
    const float* __restrict__ bias, int N,
    bf16_t* __restrict__ outA, bf16_t* __restrict__ vT)
{
    extern __shared__ bf16_t sm[];
    bf16_t* xs  = sm;             // [64][104]
    bf16_t* wsh = sm + 64 * 104;  // [N][104]
    int tid = threadIdx.x;
    int t0 = blockIdx.x * 64;

    const uint4* xg = (const uint4*)(X + (size_t)t0 * 96);
    uint4* xsv = (uint4*)xs;
    for (int i = tid; i < 768; i += 256) {
        int row = i / 12, c16 = i % 12;
        xsv[row * 13 + c16] = xg[i];
    }
    const uint4* wg = (const uint4*)WT;
    uint4* wsv = (uint4*)wsh;
    for (int i = tid; i < N * 12; i += 256) {
        int row = i / 12, c16 = i % 12;
        wsv[row * 13 + c16] = wg[i];
    }
    __syncthreads();

    int w = tid >> 6, l = tid & 63;
    int lm = l & 15, lk = (l >> 4) * 8;
    int m0 = w * 16;
    bf16x8 a[3];
#pragma unroll
    for (int kk = 0; kk < 3; ++kk)
        a[kk] = *(const bf16x8*)(xs + (m0 + lm) * 104 + kk * 32 + lk);

    int trow[4], twin[4], tm[4];
#pragma unroll
    for (int r = 0; r < 4; ++r) {
        int t = t0 + m0 + (l >> 4) * 4 + r;
        trow[r] = t; twin[r] = t / 150; tm[r] = t - twin[r] * 150;
    }

    int ntiles = N >> 4;
    for (int ti = 0; ti < ntiles; ++ti) {
        int n0 = ti * 16;
        f32x4 c = {0.f, 0.f, 0.f, 0.f};
        const bf16_t* wp = wsh + (size_t)(n0 + lm) * 104 + lk;
        c = __builtin_amdgcn_mfma_f32_16x16x32_bf16(a[0], *(const bf16x8*)(wp), c, 0, 0, 0);
        c = __builtin_amdgcn_mfma_f32_16x16x32_bf16(a[1], *(const bf16x8*)(wp + 32), c, 0, 0, 0);
        c = __builtin_amdgcn_mfma_f32_16x16x32_bf16(a[2], *(const bf16x8*)(wp + 64), c, 0, 0, 0);
        int n = n0 + lm;
        float bs = bias[n];
        if (n < 96) {
#pragma unroll
            for (int r = 0; r < 4; ++r)
                outA[(size_t)trow[r] * 96 + n] = (bf16_t)(c[r] + bs);
        } else {
            int cc = n - 96;
#pragma unroll
            for (int r = 0; r < 4; ++r)
                vT[((size_t)twin[r] * 96 + cc) * 160 + tm[r]] = (bf16_t)(c[r] + bs);
        }
    }
}

// ---------------------------------------------------------------------------
// K34: MFMA attention, one block (6 waves) per window. K staged in LDS once
// ([160][104] bf16, rows>=150 zeroed); each wave owns row-tiles wv, wv+6.
// P/O round-trip through per-wave LDS scratch [16][164]. V and wproj B-frags
// straight from global (L2-hot). x2 += O@wprojT + bproj (shortcut pre-added).
// ---------------------------------------------------------------------------
__global__ __launch_bounds__(384) void k_attn_mfma(
    const bf16_t* __restrict__ qb, const bf16_t* __restrict__ kb,
    const bf16_t* __restrict__ vT, const bf16_t* __restrict__ wpjT,
    const float* __restrict__ bias_mat, const float* __restrict__ bproj,
    float* __restrict__ x2)
{
    __shared__ __align__(16) bf16_t kls[160 * 104];        // 33280 B
    __shared__ __align__(16) bf16_t pls_all[6 * 16 * 164]; // 31488 B
    int win = blockIdx.x;
    int tid = threadIdx.x;
    int wv = tid >> 6, l = tid & 63;
    int lm = l & 15, lq = l >> 4, lk8 = lq * 8;
    size_t wbase = (size_t)win * 150 * 96;
    size_t vbase = (size_t)win * 96 * 160;
    bf16_t* pls = pls_all + wv * 16 * 164;

    // ---- stage K into LDS (coalesced 16B chunks), zero pad rows 150..159 ----
    {
        const uint4* src = (const uint4*)(kb + wbase);   // 150 rows x 12 chunks
        for (int i = tid; i < 1800; i += 384) {
            int row = i / 12, c = i % 12;
            *(uint4*)(kls + row * 104 + c * 8) = src[i];
        }
        uint4 z = {0, 0, 0, 0};
        for (int i = tid; i < 130; i += 384) {           // 10 rows x 13 chunks
            int row = 150 + i / 13, c = i % 13;
            *(uint4*)(kls + row * 104 + c * 8) = z;
        }
    }
    __syncthreads();

    for (int ti = wv; ti < 10; ti += 6) {
        int r0 = ti * 16;

        // ---- S = Q K^T (Q A-frags from global, K B-frags from LDS) ----
        bf16x8 aq[3];
#pragma unroll
        for (int kk = 0; kk < 3; ++kk)
            aq[kk] = *(const bf16x8*)(qb + wbase + (size_t)(r0 + lm) * 96 + kk * 32 + lk8);

        f32x4 s[10];
#pragma unroll
        for (int nt = 0; nt < 10; ++nt) {
            f32x4 acc = {0.f, 0.f, 0.f, 0.f};
            const bf16_t* kp = kls + (nt * 16 + lm) * 104 + lk8;
            acc = __builtin_amdgcn_mfma_f32_16x16x32_bf16(aq[0], *(const bf16x8*)(kp), acc, 0, 0, 0);
            acc = __builtin_amdgcn_mfma_f32_16x16x32_bf16(aq[1], *(const bf16x8*)(kp + 32), acc, 0, 0, 0);
            acc = __builtin_amdgcn_mfma_f32_16x16x32_bf16(aq[2], *(const bf16x8*)(kp + 64), acc, 0, 0, 0);
            s[nt] = acc;
        }

        // ---- softmax (bias+mask folded into bias_mat) ----
#pragma unroll
        for (int r = 0; r < 4; ++r) {
            int grow = r0 + lq * 4 + r;
            float rowmax = -3.0e38f;
#pragma unroll
            for (int nt = 0; nt < 10; ++nt) {
                float bv = bias_mat[grow * 160 + nt * 16 + lm];
                float v = fmaf(s[nt][r], SCALE, bv);
                s[nt][r] = v;
                rowmax = fmaxf(rowmax, v);
            }
            rowmax = fmaxf(rowmax, __shfl_xor(rowmax, 1));
            rowmax = fmaxf(rowmax, __shfl_xor(rowmax, 2));
            rowmax = fmaxf(rowmax, __shfl_xor(rowmax, 4));
            rowmax = fmaxf(rowmax, __shfl_xor(rowmax, 8));
            float ssum = 0.f;
#pragma unroll
            for (int nt = 0; nt < 10; ++nt) {
                float e = __expf(s[nt][r] - rowmax);
                s[nt][r] = e;
                ssum += e;
            }
            ssum += __shfl_xor(ssum, 1);
            ssum += __shfl_xor(ssum, 2);
            ssum += __shfl_xor(ssum, 4);
            ssum += __shfl_xor(ssum, 8);
            float inv = 1.f / ssum;
            int lrow = lq * 4 + r;
#pragma unroll
            for (int nt = 0; nt < 10; ++nt)
                pls[lrow * 164 + nt * 16 + lm] = (bf16_t)(s[nt][r] * inv);
        }
        // wave-private LDS: no barrier needed (lgkmcnt orders within wave)

        // ---- O = P @ V (P A-frags from LDS, V B-frags from global) ----
        f32x4 o[6];
#pragma unroll
        for (int ct = 0; ct < 6; ++ct) o[ct] = (f32x4){0.f, 0.f, 0.f, 0.f};
#pragma unroll
        for (int kf = 0; kf < 5; ++kf) {
            bf16x8 ap = *(const bf16x8*)(pls + lm * 164 + kf * 32 + lk8);
#pragma unroll
            for (int ct = 0; ct < 6; ++ct) {
                const bf16_t* vp = vT + vbase + (size_t)(ct * 16 + lm) * 160 + kf * 32 + lk8;
                o[ct] = __builtin_amdgcn_mfma_f32_16x16x32_bf16(ap, *(const bf16x8*)(vp), o[ct], 0, 0, 0);
            }
        }

        // ---- O -> LDS (A-layout staging), reuse pls as [16][104] ----
#pragma unroll
        for (int ct = 0; ct < 6; ++ct)
#pragma unroll
            for (int r = 0; r < 4; ++r)
                pls[(lq * 4 + r) * 104 + ct * 16 + lm] = (bf16_t)o[ct][r];

        // ---- x2 += O @ wprojT + bproj ----
        bf16x8 ao[3];
#pragma unroll
        for (int kk = 0; kk < 3; ++kk)
            ao[kk] = *(const bf16x8*)(pls + lm * 104 + kk * 32 + lk8);
        f32x4 pj[6];
#pragma unroll
        for (int ct = 0; ct < 6; ++ct) {
            f32x4 acc = {0.f, 0.f, 0.f, 0.f};
            const bf16_t* wp = wpjT + (size_t)(ct * 16 + lm) * 96 + lk8;
            acc = __builtin_amdgcn_mfma_f32_16x16x32_bf16(ao[0], *(const bf16x8*)(wp), acc, 0, 0, 0);
            acc = __builtin_amdgcn_mfma_f32_16x16x32_bf16(ao[1], *(const bf16x8*)(wp + 32), acc, 0, 0, 0);
            acc = __builtin_amdgcn_mfma_f32_16x16x32_bf16(ao[2], *(const bf16x8*)(wp + 64), acc, 0, 0, 0);
            pj[ct] = acc;
        }
#pragma unroll
        for (int r = 0; r < 4; ++r) {
            int gr = r0 + lq * 4 + r;
            if (gr < 150) {
                size_t t = (size_t)win * 150 + gr;
#pragma unroll
                for (int ct = 0; ct < 6; ++ct) {
                    int c = ct * 16 + lm;
                    size_t off = t * 96 + c;
                    x2[off] = x2[off] + pj[ct][r] + bproj[c];
                }
            }
        }
    }
}

// ---------------------------------------------------------------------------
// K5: MFMA MLP v2. LN in registers; hidden in 4 chunks of 96; single-buffer
// per-wave h scratch (LDS 26624 B total -> 6 blocks/CU LDS-wise); explicit
// 3-tile register lookahead on w1/w2 B-frag loads for memory-latency ILP.
// x3 = x2 + gelu(ln2(x2)@w1+b1)@w2+b2, written bf16 in SPATIAL order for conv.
// grid = 2400 (64 tokens), 256 threads = 4 waves.
// ---------------------------------------------------------------------------
__global__ __launch_bounds__(256, 5) void k_mlp_mfma(
    const float* __restrict__ x2,
    const float* __restrict__ g2, const float* __restrict__ b2,
    const bf16_t* __restrict__ w1T, const float* __restrict__ b1,
    const bf16_t* __restrict__ w2T, const float* __restrict__ b2v,
    bf16_t* __restrict__ xc)
{
    __shared__ __align__(16) bf16_t xs[64 * 104];      // 13312 B
    __shared__ __align__(16) bf16_t hs[4 * 16 * 104];  // 13312 B

    int tid = threadIdx.x;
    int t0 = blockIdx.x * 64;

    // ---- register LayerNorm: thread = (token t, quarter p) ----
    {
        int t = tid >> 2, p = tid & 3;
        float xr[24];
        const float4* xg = (const float4*)(x2 + (size_t)(t0 + t) * 96 + p * 24);
#pragma unroll
        for (int j4 = 0; j4 < 6; ++j4) {
            float4 v = xg[j4];
            xr[j4 * 4 + 0] = v.x; xr[j4 * 4 + 1] = v.y;
            xr[j4 * 4 + 2] = v.z; xr[j4 * 4 + 3] = v.w;
        }
        float s = 0.f, s2 = 0.f;
#pragma unroll
        for (int j = 0; j < 24; ++j) { s += xr[j]; s2 += xr[j] * xr[j]; }
        s += __shfl_xor(s, 1); s += __shfl_xor(s, 2);
        s2 += __shfl_xor(s2, 1); s2 += __shfl_xor(s2, 2);
        float m = s * (1.f / 96.f);
        float var = s2 * (1.f / 96.f) - m * m;
        float rstd = rsqrtf(var + 1e-5f);

        const float4* gg = (const float4*)(g2 + p * 24);
        const float4* bb = (const float4*)(b2 + p * 24);
        bf16_t tmp[24];
#pragma unroll
        for (int j4 = 0; j4 < 6; ++j4) {
            float4 g = gg[j4], bv = bb[j4];
            tmp[j4 * 4 + 0] = (bf16_t)((xr[j4 * 4 + 0] - m) * rstd * g.x + bv.x);
            tmp[j4 * 4 + 1] = (bf16_t)((xr[j4 * 4 + 1] - m) * rstd * g.y + bv.y);
            tmp[j4 * 4 + 2] = (bf16_t)((xr[j4 * 4 + 2] - m) * rstd * g.z + bv.z);
            tmp[j4 * 4 + 3] = (bf16_t)((xr[j4 * 4 + 3] - m) * rstd * g.w + bv.w);
        }
        uint4* dst = (uint4*)(xs + t * 104 + p * 24);   // 48B per quarter
        const uint4* src = (const uint4*)tmp;
        dst[0] = src[0]; dst[1] = src[1]; dst[2] = src[2];
    }
    // NO __syncthreads(): token rows [16w,16w+16) of xs are written by tids
    // [64w,64w+64) = wave w itself; in-wave DS ordering suffices.

    int w = tid >> 6, l = tid & 63;
    int lm = l & 15, lq = l >> 4, lk = lq * 8;
    int m0 = w * 16;
    bf16_t* hw = hs + w * 16 * 104;

    bf16x8 a[3];
#pragma unroll
    for (int kk = 0; kk < 3; ++kk)
        a[kk] = *(const bf16x8*)(xs + (m0 + lm) * 104 + kk * 32 + lk);

    f32x4 acc2[6];
#pragma unroll
    for (int i = 0; i < 6; ++i) acc2[i] = (f32x4){0.f, 0.f, 0.f, 0.f};

#pragma unroll
    for (int cc = 0; cc < 4; ++cc) {
        // ---- stage1: h = gelu(x @ w1_cc + b1), 3-tile lookahead ----
        float bsv[6];
#pragma unroll
        for (int j = 0; j < 6; ++j) bsv[j] = b1[cc * 96 + j * 16 + lm];
        bf16x8 wf[3][3];
#pragma unroll
        for (int j = 0; j < 3; ++j) {
            const bf16_t* p = w1T + (size_t)(cc * 96 + j * 16 + lm) * 96 + lk;
            wf[j][0] = *(const bf16x8*)(p);
            wf[j][1] = *(const bf16x8*)(p + 32);
            wf[j][2] = *(const bf16x8*)(p + 64);
        }
#pragma unroll
        for (int ti = 0; ti < 6; ++ti) {
            f32x4 c1 = {0.f, 0.f, 0.f, 0.f};
            c1 = __builtin_amdgcn_mfma_f32_16x16x32_bf16(a[0], wf[ti % 3][0], c1, 0, 0, 0);
            c1 = __builtin_amdgcn_mfma_f32_16x16x32_bf16(a[1], wf[ti % 3][1], c1, 0, 0, 0);
            c1 = __builtin_amdgcn_mfma_f32_16x16x32_bf16(a[2], wf[ti % 3][2], c1, 0, 0, 0);
            if (ti < 3) {
                const bf16_t* p = w1T + (size_t)(cc * 96 + (ti + 3) * 16 + lm) * 96 + lk;
                wf[ti][0] = *(const bf16x8*)(p);
                wf[ti][1] = *(const bf16x8*)(p + 32);
                wf[ti][2] = *(const bf16x8*)(p + 64);
            }
#pragma unroll
            for (int r = 0; r < 4; ++r)
                hw[(lq * 4 + r) * 104 + ti * 16 + lm] = (bf16_t)gelu_f(c1[r] + bsv[ti]);
        }

        // ---- stage2: acc2 += h_cc @ w2_cc, 3-tile lookahead ----
        bf16x8 vf[3][3];
#pragma unroll
        for (int j = 0; j < 3; ++j) {
            const bf16_t* p = w2T + (size_t)(j * 16 + lm) * 384 + cc * 96 + lk;
            vf[j][0] = *(const bf16x8*)(p);
            vf[j][1] = *(const bf16x8*)(p + 32);
            vf[j][2] = *(const bf16x8*)(p + 64);
        }
        bf16x8 ha[3];
#pragma unroll
        for (int kk = 0; kk < 3; ++kk)
            ha[kk] = *(const bf16x8*)(hw + lm * 104 + kk * 32 + lk);
#pragma unroll
        for (int ti = 0; ti < 6; ++ti) {
            acc2[ti] = __builtin_amdgcn_mfma_f32_16x16x32_bf16(ha[0], vf[ti % 3][0], acc2[ti], 0, 0, 0);
            acc2[ti] = __builtin_amdgcn_mfma_f32_16x16x32_bf16(ha[1], vf[ti % 3][1], acc2[ti], 0, 0, 0);
            acc2[ti] = __builtin_amdgcn_mfma_f32_16x16x32_bf16(ha[2], vf[ti % 3][2], acc2[ti], 0, 0, 0);
            if (ti < 3) {
                const bf16_t* p = w2T + (size_t)((ti + 3) * 16 + lm) * 384 + cc * 96 + lk;
                vf[ti][0] = *(const bf16x8*)(p);
                vf[ti][1] = *(const bf16x8*)(p + 32);
                vf[ti][2] = *(const bf16x8*)(p + 64);
            }
        }
    }

    // epilogue: residual + bias; write bf16 in spatial order for the conv
    int srow[4];
#pragma unroll
    for (int r = 0; r < 4; ++r) {
        int t = t0 + m0 + (l >> 4) * 4 + r;
        int win = t / 150, nn = t - win * 150;
        int b = win >> 9, d0 = (win >> 6) & 7, h0 = (win >> 3) & 7, w0 = win & 7;
        int wd = nn / 30, rem = nn % 30, wh = rem / 5, ww = rem % 5;
        srow[r] = ((b * 40 + d0 * 5 + wd) * 48 + h0 * 6 + wh) * 40 + w0 * 5 + ww;
    }
#pragma unroll
    for (int ti = 0; ti < 6; ++ti) {
        int n = ti * 16 + lm;
        float bs = b2v[n];
#pragma unroll
        for (int r = 0; r < 4; ++r) {
            int t = t0 + m0 + (l >> 4) * 4 + r;
            size_t o = (size_t)t * 96 + n;
            xc[(size_t)srow[r] * 96 + n] = (bf16_t)(x2[o] + acc2[ti][r] + bs);
        }
    }
}

// ---------------------------------------------------------------------------
// K6: 3x3x3 conv (96 -> 3), zero pad. Input xc: bf16, spatial (b,d,h,w,c).
// Weights cwT[kk][oc][ci] staged in LDS, read as broadcast float4.
// grid = 600, 256 threads (one thread per spatial point, 3 out channels).
// ---------------------------------------------------------------------------
__global__ __launch_bounds__(256) void k_conv(
    const bf16_t* __restrict__ xc, const float* __restrict__ cwT,
    const float* __restrict__ cb, float* __restrict__ out)
{
    __shared__ float wl[7776];   // [kk][oc][ci]
    int tid = threadIdx.x;
    for (int i = tid; i < 7776; i += 256) wl[i] = cwT[i];
    __syncthreads();

    int s = blockIdx.x * 256 + tid;
    int b = s / 76800, r = s % 76800;
    int d = r / 1920, h = (r / 40) % 48, w = r % 40;
    float a0 = 0.f, a1 = 0.f, a2 = 0.f;

    for (int dd = 0; dd < 3; ++dd) {
        int d2 = d + dd - 1;
        if ((unsigned)d2 >= 40u) continue;
        for (int hh = 0; hh < 3; ++hh) {
            int h2 = h + hh - 1;
            if ((unsigned)h2 >= 48u) continue;
            for (int ww = 0; ww < 3; ++ww) {
                int w2 = w + ww - 1;
                if ((unsigned)w2 >= 40u) continue;
                int kk = (dd * 3 + hh) * 3 + ww;
                const bf16x8* xp = (const bf16x8*)
                    (xc + ((size_t)((b * 40 + d2) * 48 + h2) * 40 + w2) * 96);
                const float* wk = wl + kk * 288;
#pragma unroll
                for (int c8 = 0; c8 < 12; ++c8) {
                    bf16x8 xv = xp[c8];
                    float x0 = (float)xv[0], x1 = (float)xv[1];
                    float x2v = (float)xv[2], x3 = (float)xv[3];
                    float x4 = (float)xv[4], x5 = (float)xv[5];
                    float x6 = (float)xv[6], x7 = (float)xv[7];
                    float4 wa0 = *(const float4*)(wk + c8 * 8);
                    float4 wb0 = *(const float4*)(wk + c8 * 8 + 4);
                    float4 wa1 = *(const float4*)(wk + 96 + c8 * 8);
                    float4 wb1 = *(const float4*)(wk + 96 + c8 * 8 + 4);
                    float4 wa2 = *(const float4*)(wk + 192 + c8 * 8);
                    float4 wb2 = *(const float4*)(wk + 192 + c8 * 8 + 4);
                    a0 += x0 * wa0.x + x1 * wa0.y + x2v * wa0.z + x3 * wa0.w
                        + x4 * wb0.x + x5 * wb0.y + x6 * wb0.z + x7 * wb0.w;
                    a1 += x0 * wa1.x + x1 * wa1.y + x2v * wa1.z + x3 * wa1.w
                        + x4 * wb1.x + x5 * wb1.y + x6 * wb1.z + x7 * wb1.w;
                    a2 += x0 * wa2.x + x1 * wa2.y + x2v * wa2.z + x3 * wa2.w
                        + x4 * wb2.x + x5 * wb2.y + x6 * wb2.z + x7 * wb2.w;
                }
            }
        }
    }
    out[(size_t)(b * 3 + 0) * 76800 + r] = a0 + cb[0];
    out[(size_t)(b * 3 + 1) * 76800 + r] = a1 + cb[1];
    out[(size_t)(b * 3 + 2) * 76800 + r] = a2 + cb[2];
}

// ---------------------------------------------------------------------------
extern "C" void kernel_launch(void* const* d_in, const int* in_sizes, int n_in,
                              void* d_out, int out_size, void* d_ws, size_t ws_size,
                              hipStream_t stream)
{
    (void)in_sizes; (void)n_in; (void)out_size;

    const float* Im  = (const float*)d_in[0];
    const float* If  = (const float*)d_in[1];
    const float* g1q = (const float*)d_in[2];
    const float* b1q = (const float*)d_in[3];
    const float* g1k = (const float*)d_in[4];
    const float* b1k = (const float*)d_in[5];
    const float* wq  = (const float*)d_in[6];
    const float* bq  = (const float*)d_in[7];
    const float* wkv = (const float*)d_in[8];
    const float* bkv = (const float*)d_in[9];
    const float* wpj = (const float*)d_in[10];
    const float* bpj = (const float*)d_in[11];
    const float* rb  = (const float*)d_in[12];
    const float* g2  = (const float*)d_in[13];
    const float* b2  = (const float*)d_in[14];
    const float* w1  = (const float*)d_in[15];
    const float* b1  = (const float*)d_in[16];
    const float* w2  = (const float*)d_in[17];
    const float* b2v = (const float*)d_in[18];
    const float* cw  = (const float*)d_in[19];
    const float* cb  = (const float*)d_in[20];
    float* out = (float*)d_out;

    size_t U = (size_t)NTOK * 96;
    if (ws_size < 4 * U * sizeof(float)) return;
    float* ws = (float*)d_ws;
    bf16_t* xlnb = (bf16_t*)ws;                        // U bf16 (-> xc later)
    bf16_t* ylnb = (bf16_t*)(ws + U / 2);              // U bf16
    bf16_t* qb   = (bf16_t*)(ws + U);                  // U bf16
    bf16_t* kb   = (bf16_t*)(ws + 3 * U / 2);          // U bf16
    bf16_t* vT   = (bf16_t*)(ws + 2 * U);              // 1024*96*160 bf16
    float*  wtail = ws + 2 * U + (1024 * 96 * 160) / 2;
    bf16_t* wqT  = (bf16_t*)wtail;                     // 9216
    bf16_t* wkvT = wqT + 9216;                         // 18432
    bf16_t* w1T  = wkvT + 18432;                       // 36864
    bf16_t* w2T  = w1T + 36864;                        // 36864
    bf16_t* wpjT = w2T + 36864;                        // 9216
    float*  bias_mat = (float*)(wpjT + 9216 + 2);      // 25600 fp32
    float*  cwT  = bias_mat + 25600;                   // 7776 fp32
    float*  x2f  = ws + 3 * U;                         // U fp32
    bf16_t* xc   = (bf16_t*)ws;                        // U bf16, spatial order

    k_prep_weights<<<144, 256, 0, stream>>>(wq, wkv, w1, w2, wpj, rb, cw,
                                            wqT, wkvT, w1T, w2T, wpjT,
                                            bias_mat, cwT);
    k_ln_transpose<<<3840, 256, 0, stream>>>(Im, If, g1q, b1q, g1k, b1k,
                                             xlnb, ylnb, x2f);
    size_t shm_q  = (size_t)(64 * 104 + 96 * 104) * sizeof(bf16_t);   // 33280
    size_t shm_kv = (size_t)(64 * 104 + 192 * 104) * sizeof(bf16_t);  // 53248
    k_proj_mfma<<<2400, 256, shm_q, stream>>>(xlnb, wqT, bq, 96, qb, nullptr);
    k_proj_mfma<<<2400, 256, shm_kv, stream>>>(ylnb, wkvT, bkv, 192, kb, vT);
    k_attn_mfma<<<1024, 384, 0, stream>>>(qb, kb, vT, wpjT, bias_mat, bpj, x2f);
    k_mlp_mfma<<<2400, 256, 0, stream>>>(x2f, g2, b2, w1T, b1, w2T, b2v, xc);
    k_conv<<<600, 256, 0, stream>>>(xc, cwT, cb, out);
}

// Round 4
// 581.502 us; speedup vs baseline: 1.1996x; 1.1745x over previous
//
#include <hip/hip_runtime.h>
#include <math.h>

// ---------------------------------------------------------------------------
// Swin-3D cross-attention block. Round 10: identical resubmission of the
// Round-9 source — the bench died with an infra-level container error
// (no compile/verify/profile happened), same as Round 0/7. Re-measuring.
//  - k_mlp v3: one wave = 32 tokens (2 M-tiles). Weight loads amortized 2x,
//    12 independent acc chains, half the waves. Grid 1200, LDS 53KB,
//    launch_bounds(256,3) so the allocator can keep fragments resident.
//  - k_conv v2: 4 lanes per point (24 ci each), shfl reduce, 2400 blocks
//    (was 600 -> occupancy 21%). Lane p<3 writes output plane p.
// Token order = window-partitioned:
//   win = ((b*8 + d/5)*8 + h/6)*8 + w/5 ; t = ((d%5)*6 + h%6)*5 + w%5
// ---------------------------------------------------------------------------

static constexpr int NTOK = 153600;
static constexpr float SCALE = 0.10206207261596575f; // 96^-0.5

typedef __bf16 bf16_t;
typedef __bf16 bf16x8 __attribute__((ext_vector_type(8)));
typedef float f32x4 __attribute__((ext_vector_type(4)));

__device__ __forceinline__ int tok_index(int b, int d, int h, int w) {
    int d0 = d / 5, wd = d % 5;
    int h0 = h / 6, wh = h % 6;
    int w0 = w / 5, ww = w % 5;
    int win = ((b * 8 + d0) * 8 + h0) * 8 + w0;
    return win * 150 + (wd * 6 + wh) * 5 + ww;
}

__device__ __forceinline__ float gelu_f(float u) {
    float u2 = u * u;
    float arg = u * fmaf(0.0713549f, u2, 1.5957691f);
    float e = __expf(arg);
    float r = __builtin_amdgcn_rcpf(e + 1.f);
    return fmaf(-u, r, u);
}

// ---------------------------------------------------------------------------
// K0: weight convert/transpose bf16 [n][k]; fp32 bias matrix [160][160];
// conv weights re-laid to cwT[kk][oc][ci] (ci-contiguous for float4 reads).
// ---------------------------------------------------------------------------
__global__ __launch_bounds__(256) void k_prep_weights(
    const float* __restrict__ wq, const float* __restrict__ wkv,
    const float* __restrict__ w1, const float* __restrict__ w2,
    const float* __restrict__ wproj, const float* __restrict__ relb,
    const float* __restrict__ cw,
    bf16_t* wqT, bf16_t* wkvT, bf16_t* w1T, bf16_t* w2T, bf16_t* wpjT,
    float* bias_mat, float* cwT)
{
    int i = blockIdx.x * 256 + threadIdx.x;
    if (i < 9216)  wqT[i]  = (bf16_t)wq[(i % 96) * 96 + i / 96];
    if (i < 18432) wkvT[i] = (bf16_t)wkv[(i % 96) * 192 + i / 96];
    if (i < 36864) w1T[i]  = (bf16_t)w1[(i % 96) * 384 + i / 96];
    if (i < 36864) w2T[i]  = (bf16_t)w2[(i % 384) * 96 + i / 384];
    if (i < 9216)  wpjT[i] = (bf16_t)wproj[(i % 96) * 96 + i / 96];
    if (i < 25600) {
        int row = i / 160, col = i % 160;
        float v;
        if (col >= 150) v = -1e30f;
        else if (row >= 150) v = 0.f;
        else {
            int wd1 = row / 30, rh1 = row % 30, wh1 = rh1 / 5, ww1 = rh1 % 5;
            int wd2 = col / 30, rh2 = col % 30, wh2 = rh2 / 5, ww2 = rh2 % 5;
            int idx = (wd1 - wd2 + 4) * 99 + (wh1 - wh2 + 5) * 9 + (ww1 - ww2 + 4);
            v = relb[idx];
        }
        bias_mat[i] = v;
    }
    if (i < 7776) {
        int kk = i / 288, rem = i % 288;
        int oc = rem / 96, ci = rem % 96;
        cwT[i] = cw[oc * 2592 + ci * 27 + kk];
    }
}

// ---------------------------------------------------------------------------
// K1: transpose->token order + LayerNorm (bf16 out) + fp32 Im shortcut to x2.
// grid = 3840, 256 threads.
// ---------------------------------------------------------------------------
__global__ __launch_bounds__(256) void k_ln_transpose(
    const float* __restrict__ Im, const float* __restrict__ If,
    const float* __restrict__ g1q, const float* __restrict__ b1q,
    const float* __restrict__ g1k, const float* __restrict__ b1k,
    bf16_t* __restrict__ xln, bf16_t* __restrict__ yln,
    float* __restrict__ x2s)
{
    __shared__ float tile[40 * 97];
    __shared__ float mean_s[40], rstd_s[40];
    int blk = blockIdx.x;
    int b = blk / (40 * 48);
    int rem = blk % (40 * 48);
    int d = rem / 48, h = rem % 48;
    int tid = threadIdx.x;

    for (int pass = 0; pass < 2; ++pass) {
        const float* src = pass ? If : Im;
        const float* gg = pass ? g1k : g1q;
        const float* bb = pass ? b1k : b1q;
        bf16_t* dst = pass ? yln : xln;

        for (int i = tid; i < 96 * 40; i += 256) {
            int c = i / 40, w = i % 40;
            tile[w * 97 + c] = src[(size_t)(b * 96 + c) * 76800 + d * 1920 + h * 40 + w];
        }
        __syncthreads();
        if (tid < 40) {
            float s = 0.f, s2 = 0.f;
            for (int c = 0; c < 96; ++c) {
                float v = tile[tid * 97 + c];
                s += v; s2 += v * v;
            }
            float m = s * (1.f / 96.f);
            float var = s2 * (1.f / 96.f) - m * m;
            mean_s[tid] = m;
            rstd_s[tid] = rsqrtf(var + 1e-5f);
        }
        __syncthreads();
        for (int i = tid; i < 40 * 96; i += 256) {
            int w = i / 96, c = i % 96;
            int tok = tok_index(b, d, h, w);
            float raw = tile[w * 97 + c];
            float v = (raw - mean_s[w]) * rstd_s[w] * gg[c] + bb[c];
            dst[(size_t)tok * 96 + c] = (bf16_t)v;
            if (pass == 0) x2s[(size_t)tok * 96 + c] = raw;   // shortcut
        }
        __syncthreads();
    }
}

// ---------------------------------------------------------------------------
// K2: MFMA projection. WT is [N][96] bf16, staged once per block into LDS
// ([N][104] padded) so B-frags come from LDS, not per-MFMA global loads.
// N=96 -> qb only. N=192 -> n<96 writes kb [t][c]; n>=96 writes vT.
// grid = 2400 (64 tokens/block), 256 threads = 4 waves.
// dynamic LDS = (64*104 + N*104)*2 B.
// ---------------------------------------------------------------------------
__global__ __launch_bounds__(256) void k_proj_mfma(
    const bf16_t* __restrict__ X, const bf16_t* __restrict__ WT,
    const float* __restrict__ bias, int N,
    bf16_t* __restrict__ outA, bf16_t* __restrict__ vT)
{
    extern __shared__ bf16_t sm[];
    bf16_t* xs  = sm;             // [64][104]
    bf16_t* wsh = sm + 64 * 104;  // [N][104]
    int tid = threadIdx.x;
    int t0 = blockIdx.x * 64;

    const uint4* xg = (const uint4*)(X + (size_t)t0 * 96);
    uint4* xsv = (uint4*)xs;
    for (int i = tid; i < 768; i += 256) {
        int row = i / 12, c16 = i % 12;
        xsv[row * 13 + c16] = xg[i];
    }
    const uint4* wg = (const uint4*)WT;
    uint4* wsv = (uint4*)wsh;
    for (int i = tid; i < N * 12; i += 256) {
        int row = i / 12, c16 = i % 12;
        wsv[row * 13 + c16] = wg[i];
    }
    __syncthreads();

    int w = tid >> 6, l = tid & 63;
    int lm = l & 15, lk = (l >> 4) * 8;
    int m0 = w * 16;
    bf16x8 a[3];
#pragma unroll
    for (int kk = 0; kk < 3; ++kk)
        a[kk] = *(const bf16x8*)(xs + (m0 + lm) * 104 + kk * 32 + lk);

    int trow[4], twin[4], tm[4];
#pragma unroll
    for (int r = 0; r < 4; ++r) {
        int t = t0 + m0 + (l >> 4) * 4 + r;
        trow[r] = t; twin[r] = t / 150; tm[r] = t - twin[r] * 150;
    }

    int ntiles = N >> 4;
    for (int ti = 0; ti < ntiles; ++ti) {
        int n0 = ti * 16;
        f32x4 c = {0.f, 0.f, 0.f, 0.f};
        const bf16_t* wp = wsh + (size_t)(n0 + lm) * 104 + lk;
        c = __builtin_amdgcn_mfma_f32_16x16x32_bf16(a[0], *(const bf16x8*)(wp), c, 0, 0, 0);
        c = __builtin_amdgcn_mfma_f32_16x16x32_bf16(a[1], *(const bf16x8*)(wp + 32), c, 0, 0, 0);
        c = __builtin_amdgcn_mfma_f32_16x16x32_bf16(a[2], *(const bf16x8*)(wp + 64), c, 0, 0, 0);
        int n = n0 + lm;
        float bs = bias[n];
        if (n < 96) {
#pragma unroll
            for (int r = 0; r < 4; ++r)
                outA[(size_t)trow[r] * 96 + n] = (bf16_t)(c[r] + bs);
        } else {
            int cc = n - 96;
#pragma unroll
            for (int r = 0; r < 4; ++r)
                vT[((size_t)twin[r] * 96 + cc) * 160 + tm[r]] = (bf16_t)(c[r] + bs);
        }
    }
}

// ---------------------------------------------------------------------------
// K34: MFMA attention, one block (6 waves) per window. K staged in LDS once
// ([160][104] bf16, rows>=150 zeroed); each wave owns row-tiles wv, wv+6.
// P/O round-trip through per-wave LDS scratch [16][164]. V and wproj B-frags
// straight from global (L2-hot). x2 += O@wprojT + bproj (shortcut pre-added).
// ---------------------------------------------------------------------------
__global__ __launch_bounds__(384) void k_attn_mfma(
    const bf16_t* __restrict__ qb, const bf16_t* __restrict__ kb,
    const bf16_t* __restrict__ vT, const bf16_t* __restrict__ wpjT,
    const float* __restrict__ bias_mat, const float* __restrict__ bproj,
    float* __restrict__ x2)
{
    __shared__ __align__(16) bf16_t kls[160 * 104];        // 33280 B
    __shared__ __align__(16) bf16_t pls_all[6 * 16 * 164]; // 31488 B
    int win = blockIdx.x;
    int tid = threadIdx.x;
    int wv = tid >> 6, l = tid & 63;
    int lm = l & 15, lq = l >> 4, lk8 = lq * 8;
    size_t wbase = (size_t)win * 150 * 96;
    size_t vbase = (size_t)win * 96 * 160;
    bf16_t* pls = pls_all + wv * 16 * 164;

    // ---- stage K into LDS (coalesced 16B chunks), zero pad rows 150..159 ----
    {
        const uint4* src = (const uint4*)(kb + wbase);   // 150 rows x 12 chunks
        for (int i = tid; i < 1800; i += 384) {
            int row = i / 12, c = i % 12;
            *(uint4*)(kls + row * 104 + c * 8) = src[i];
        }
        uint4 z = {0, 0, 0, 0};
        for (int i = tid; i < 130; i += 384) {           // 10 rows x 13 chunks
            int row = 150 + i / 13, c = i % 13;
            *(uint4*)(kls + row * 104 + c * 8) = z;
        }
    }
    __syncthreads();

    for (int ti = wv; ti < 10; ti += 6) {
        int r0 = ti * 16;

        // ---- S = Q K^T (Q A-frags from global, K B-frags from LDS) ----
        bf16x8 aq[3];
#pragma unroll
        for (int kk = 0; kk < 3; ++kk)
            aq[kk] = *(const bf16x8*)(qb + wbase + (size_t)(r0 + lm) * 96 + kk * 32 + lk8);

        f32x4 s[10];
#pragma unroll
        for (int nt = 0; nt < 10; ++nt) {
            f32x4 acc = {0.f, 0.f, 0.f, 0.f};
            const bf16_t* kp = kls + (nt * 16 + lm) * 104 + lk8;
            acc = __builtin_amdgcn_mfma_f32_16x16x32_bf16(aq[0], *(const bf16x8*)(kp), acc, 0, 0, 0);
            acc = __builtin_amdgcn_mfma_f32_16x16x32_bf16(aq[1], *(const bf16x8*)(kp + 32), acc, 0, 0, 0);
            acc = __builtin_amdgcn_mfma_f32_16x16x32_bf16(aq[2], *(const bf16x8*)(kp + 64), acc, 0, 0, 0);
            s[nt] = acc;
        }

        // ---- softmax (bias+mask folded into bias_mat) ----
#pragma unroll
        for (int r = 0; r < 4; ++r) {
            int grow = r0 + lq * 4 + r;
            float rowmax = -3.0e38f;
#pragma unroll
            for (int nt = 0; nt < 10; ++nt) {
                float bv = bias_mat[grow * 160 + nt * 16 + lm];
                float v = fmaf(s[nt][r], SCALE, bv);
                s[nt][r] = v;
                rowmax = fmaxf(rowmax, v);
            }
            rowmax = fmaxf(rowmax, __shfl_xor(rowmax, 1));
            rowmax = fmaxf(rowmax, __shfl_xor(rowmax, 2));
            rowmax = fmaxf(rowmax, __shfl_xor(rowmax, 4));
            rowmax = fmaxf(rowmax, __shfl_xor(rowmax, 8));
            float ssum = 0.f;
#pragma unroll
            for (int nt = 0; nt < 10; ++nt) {
                float e = __expf(s[nt][r] - rowmax);
                s[nt][r] = e;
                ssum += e;
            }
            ssum += __shfl_xor(ssum, 1);
            ssum += __shfl_xor(ssum, 2);
            ssum += __shfl_xor(ssum, 4);
            ssum += __shfl_xor(ssum, 8);
            float inv = 1.f / ssum;
            int lrow = lq * 4 + r;
#pragma unroll
            for (int nt = 0; nt < 10; ++nt)
                pls[lrow * 164 + nt * 16 + lm] = (bf16_t)(s[nt][r] * inv);
        }
        // wave-private LDS: no barrier needed (lgkmcnt orders within wave)

        // ---- O = P @ V (P A-frags from LDS, V B-frags from global) ----
        f32x4 o[6];
#pragma unroll
        for (int ct = 0; ct < 6; ++ct) o[ct] = (f32x4){0.f, 0.f, 0.f, 0.f};
#pragma unroll
        for (int kf = 0; kf < 5; ++kf) {
            bf16x8 ap = *(const bf16x8*)(pls + lm * 164 + kf * 32 + lk8);
#pragma unroll
            for (int ct = 0; ct < 6; ++ct) {
                const bf16_t* vp = vT + vbase + (size_t)(ct * 16 + lm) * 160 + kf * 32 + lk8;
                o[ct] = __builtin_amdgcn_mfma_f32_16x16x32_bf16(ap, *(const bf16x8*)(vp), o[ct], 0, 0, 0);
            }
        }

        // ---- O -> LDS (A-layout staging), reuse pls as [16][104] ----
#pragma unroll
        for (int ct = 0; ct < 6; ++ct)
#pragma unroll
            for (int r = 0; r < 4; ++r)
                pls[(lq * 4 + r) * 104 + ct * 16 + lm] = (bf16_t)o[ct][r];

        // ---- x2 += O @ wprojT + bproj ----
        bf16x8 ao[3];
#pragma unroll
        for (int kk = 0; kk < 3; ++kk)
            ao[kk] = *(const bf16x8*)(pls + lm * 104 + kk * 32 + lk8);
        f32x4 pj[6];
#pragma unroll
        for (int ct = 0; ct < 6; ++ct) {
            f32x4 acc = {0.f, 0.f, 0.f, 0.f};
            const bf16_t* wp = wpjT + (size_t)(ct * 16 + lm) * 96 + lk8;
            acc = __builtin_amdgcn_mfma_f32_16x16x32_bf16(ao[0], *(const bf16x8*)(wp), acc, 0, 0, 0);
            acc = __builtin_amdgcn_mfma_f32_16x16x32_bf16(ao[1], *(const bf16x8*)(wp + 32), acc, 0, 0, 0);
            acc = __builtin_amdgcn_mfma_f32_16x16x32_bf16(ao[2], *(const bf16x8*)(wp + 64), acc, 0, 0, 0);
            pj[ct] = acc;
        }
#pragma unroll
        for (int r = 0; r < 4; ++r) {
            int gr = r0 + lq * 4 + r;
            if (gr < 150) {
                size_t t = (size_t)win * 150 + gr;
#pragma unroll
                for (int ct = 0; ct < 6; ++ct) {
                    int c = ct * 16 + lm;
                    size_t off = t * 96 + c;
                    x2[off] = x2[off] + pj[ct][r] + bproj[c];
                }
            }
        }
    }
}

// ---------------------------------------------------------------------------
// K5: MFMA MLP v3. One wave = 32 tokens (2 M-tiles): weight B-frags loaded
// once per n-tile and reused for both M-tiles (halves weight-load traffic),
// 12 independent acc chains. LN in registers (thread = token half).
// LDS = 26624 (xs[128][104]) + 26624 (hs 4x[32][104]) = 53248 B -> 3 blk/CU.
// x3 = x2 + gelu(ln2(x2)@w1+b1)@w2+b2, written bf16 in SPATIAL order for conv.
// grid = 1200 (128 tokens), 256 threads = 4 waves.
// ---------------------------------------------------------------------------
__global__ __launch_bounds__(256, 3) void k_mlp_mfma(
    const float* __restrict__ x2,
    const float* __restrict__ g2, const float* __restrict__ b2,
    const bf16_t* __restrict__ w1T, const float* __restrict__ b1,
    const bf16_t* __restrict__ w2T, const float* __restrict__ b2v,
    bf16_t* __restrict__ xc)
{
    __shared__ __align__(16) bf16_t xs[128 * 104];     // 26624 B
    __shared__ __align__(16) bf16_t hs[4 * 32 * 104];  // 26624 B

    int tid = threadIdx.x;
    int t0 = blockIdx.x * 128;

    // ---- register LayerNorm: thread = (token t, half p) ----
    {
        int t = tid >> 1, p = tid & 1;
        float xr[48];
        const float4* xg = (const float4*)(x2 + (size_t)(t0 + t) * 96 + p * 48);
#pragma unroll
        for (int j4 = 0; j4 < 12; ++j4) {
            float4 v = xg[j4];
            xr[j4 * 4 + 0] = v.x; xr[j4 * 4 + 1] = v.y;
            xr[j4 * 4 + 2] = v.z; xr[j4 * 4 + 3] = v.w;
        }
        float s = 0.f, s2 = 0.f;
#pragma unroll
        for (int j = 0; j < 48; ++j) { s += xr[j]; s2 += xr[j] * xr[j]; }
        s += __shfl_xor(s, 1);
        s2 += __shfl_xor(s2, 1);
        float m = s * (1.f / 96.f);
        float var = s2 * (1.f / 96.f) - m * m;
        float rstd = rsqrtf(var + 1e-5f);

        const float4* gg = (const float4*)(g2 + p * 48);
        const float4* bb = (const float4*)(b2 + p * 48);
        bf16_t tmp[48];
#pragma unroll
        for (int j4 = 0; j4 < 12; ++j4) {
            float4 g = gg[j4], bv = bb[j4];
            tmp[j4 * 4 + 0] = (bf16_t)((xr[j4 * 4 + 0] - m) * rstd * g.x + bv.x);
            tmp[j4 * 4 + 1] = (bf16_t)((xr[j4 * 4 + 1] - m) * rstd * g.y + bv.y);
            tmp[j4 * 4 + 2] = (bf16_t)((xr[j4 * 4 + 2] - m) * rstd * g.z + bv.z);
            tmp[j4 * 4 + 3] = (bf16_t)((xr[j4 * 4 + 3] - m) * rstd * g.w + bv.w);
        }
        uint4* dst = (uint4*)(xs + t * 104 + p * 48);   // 96B per half
        const uint4* src = (const uint4*)tmp;
#pragma unroll
        for (int j = 0; j < 6; ++j) dst[j] = src[j];
    }
    // NO __syncthreads(): token rows [32w,32w+32) of xs are written by tids
    // [64w,64w+64) = wave w itself; in-wave DS ordering suffices.

    int w = tid >> 6, l = tid & 63;
    int lm = l & 15, lq = l >> 4, lk = lq * 8;
    int m0 = w * 32;
    bf16_t* hw = hs + w * 32 * 104;

    bf16x8 a[2][3];
#pragma unroll
    for (int mt = 0; mt < 2; ++mt)
#pragma unroll
        for (int kk = 0; kk < 3; ++kk)
            a[mt][kk] = *(const bf16x8*)(xs + (m0 + mt * 16 + lm) * 104 + kk * 32 + lk);

    f32x4 acc2[2][6];
#pragma unroll
    for (int mt = 0; mt < 2; ++mt)
#pragma unroll
        for (int i = 0; i < 6; ++i) acc2[mt][i] = (f32x4){0.f, 0.f, 0.f, 0.f};

#pragma unroll
    for (int cc = 0; cc < 4; ++cc) {
        // ---- stage1: h = gelu(x @ w1_cc + b1); weight triple shared by 2 M ----
#pragma unroll
        for (int ti = 0; ti < 6; ++ti) {
            int n = cc * 96 + ti * 16 + lm;
            const bf16_t* wp = w1T + (size_t)n * 96 + lk;
            bf16x8 w0 = *(const bf16x8*)(wp);
            bf16x8 w1v = *(const bf16x8*)(wp + 32);
            bf16x8 w2v = *(const bf16x8*)(wp + 64);
            float bs = b1[n];
#pragma unroll
            for (int mt = 0; mt < 2; ++mt) {
                f32x4 c1 = {0.f, 0.f, 0.f, 0.f};
                c1 = __builtin_amdgcn_mfma_f32_16x16x32_bf16(a[mt][0], w0, c1, 0, 0, 0);
                c1 = __builtin_amdgcn_mfma_f32_16x16x32_bf16(a[mt][1], w1v, c1, 0, 0, 0);
                c1 = __builtin_amdgcn_mfma_f32_16x16x32_bf16(a[mt][2], w2v, c1, 0, 0, 0);
#pragma unroll
                for (int r = 0; r < 4; ++r)
                    hw[(mt * 16 + lq * 4 + r) * 104 + ti * 16 + lm] =
                        (bf16_t)gelu_f(c1[r] + bs);
            }
        }

        // ---- stage2: acc2 += h_cc @ w2_cc ----
        bf16x8 ha[2][3];
#pragma unroll
        for (int mt = 0; mt < 2; ++mt)
#pragma unroll
            for (int kk = 0; kk < 3; ++kk)
                ha[mt][kk] = *(const bf16x8*)(hw + (mt * 16 + lm) * 104 + kk * 32 + lk);
#pragma unroll
        for (int ti = 0; ti < 6; ++ti) {
            const bf16_t* wp = w2T + (size_t)(ti * 16 + lm) * 384 + cc * 96 + lk;
            bf16x8 v0 = *(const bf16x8*)(wp);
            bf16x8 v1 = *(const bf16x8*)(wp + 32);
            bf16x8 v2 = *(const bf16x8*)(wp + 64);
#pragma unroll
            for (int mt = 0; mt < 2; ++mt) {
                acc2[mt][ti] = __builtin_amdgcn_mfma_f32_16x16x32_bf16(ha[mt][0], v0, acc2[mt][ti], 0, 0, 0);
                acc2[mt][ti] = __builtin_amdgcn_mfma_f32_16x16x32_bf16(ha[mt][1], v1, acc2[mt][ti], 0, 0, 0);
                acc2[mt][ti] = __builtin_amdgcn_mfma_f32_16x16x32_bf16(ha[mt][2], v2, acc2[mt][ti], 0, 0, 0);
            }
        }
    }

    // epilogue: residual + bias; write bf16 in spatial order for the conv
#pragma unroll
    for (int mt = 0; mt < 2; ++mt) {
        int srow[4];
#pragma unroll
        for (int r = 0; r < 4; ++r) {
            int t = t0 + m0 + mt * 16 + lq * 4 + r;
            int win = t / 150, nn = t - win * 150;
            int b = win >> 9, d0 = (win >> 6) & 7, h0 = (win >> 3) & 7, w0 = win & 7;
            int wd = nn / 30, rem = nn % 30, wh = rem / 5, ww = rem % 5;
            srow[r] = ((b * 40 + d0 * 5 + wd) * 48 + h0 * 6 + wh) * 40 + w0 * 5 + ww;
        }
#pragma unroll
        for (int ti = 0; ti < 6; ++ti) {
            int n = ti * 16 + lm;
            float bs = b2v[n];
#pragma unroll
            for (int r = 0; r < 4; ++r) {
                int t = t0 + m0 + mt * 16 + lq * 4 + r;
                size_t o = (size_t)t * 96 + n;
                xc[(size_t)srow[r] * 96 + n] = (bf16_t)(x2[o] + acc2[mt][ti][r] + bs);
            }
        }
    }
}

// ---------------------------------------------------------------------------
// K6: 3x3x3 conv (96 -> 3), zero pad. Input xc: bf16, spatial (b,d,h,w,c).
// v2: 4 lanes per point, 24 ci each (3 bf16x8 chunks); shfl_xor reduce over
// lanes 1,2; lane p<3 writes output plane p. grid = 2400 (was 600: occ 21%).
// Weights cwT[kk][oc][ci] staged in LDS; 4 distinct 16B reads/inst,
// disjoint bank quads -> conflict-free broadcast.
// ---------------------------------------------------------------------------
__global__ __launch_bounds__(256) void k_conv(
    const bf16_t* __restrict__ xc, const float* __restrict__ cwT,
    const float* __restrict__ cb, float* __restrict__ out)
{
    __shared__ float wl[7776];   // [kk][oc][ci]
    int tid = threadIdx.x;
    for (int i = tid; i < 7776; i += 256) wl[i] = cwT[i];
    __syncthreads();

    int gid = blockIdx.x * 256 + tid;
    int s = gid >> 2, p = gid & 3;          // point, ci-quarter
    int b = s / 76800, r = s % 76800;
    int d = r / 1920, h = (r / 40) % 48, w = r % 40;
    float a0 = 0.f, a1 = 0.f, a2 = 0.f;

    for (int dd = 0; dd < 3; ++dd) {
        int d2 = d + dd - 1;
        if ((unsigned)d2 >= 40u) continue;
        for (int hh = 0; hh < 3; ++hh) {
            int h2 = h + hh - 1;
            if ((unsigned)h2 >= 48u) continue;
            for (int ww = 0; ww < 3; ++ww) {
                int w2 = w + ww - 1;
                if ((unsigned)w2 >= 40u) continue;
                int kk = (dd * 3 + hh) * 3 + ww;
                const bf16x8* xp = (const bf16x8*)
                    (xc + ((size_t)((b * 40 + d2) * 48 + h2) * 40 + w2) * 96 + p * 24);
                const float* wk = wl + kk * 288 + p * 24;
#pragma unroll
                for (int c8 = 0; c8 < 3; ++c8) {
                    bf16x8 xv = xp[c8];
                    float x0 = (float)xv[0], x1 = (float)xv[1];
                    float x2v = (float)xv[2], x3 = (float)xv[3];
                    float x4 = (float)xv[4], x5 = (float)xv[5];
                    float x6 = (float)xv[6], x7 = (float)xv[7];
                    float4 wa0 = *(const float4*)(wk + c8 * 8);
                    float4 wb0 = *(const float4*)(wk + c8 * 8 + 4);
                    float4 wa1 = *(const float4*)(wk + 96 + c8 * 8);
                    float4 wb1 = *(const float4*)(wk + 96 + c8 * 8 + 4);
                    float4 wa2 = *(const float4*)(wk + 192 + c8 * 8);
                    float4 wb2 = *(const float4*)(wk + 192 + c8 * 8 + 4);
                    a0 += x0 * wa0.x + x1 * wa0.y + x2v * wa0.z + x3 * wa0.w
                        + x4 * wb0.x + x5 * wb0.y + x6 * wb0.z + x7 * wb0.w;
                    a1 += x0 * wa1.x + x1 * wa1.y + x2v * wa1.z + x3 * wa1.w
                        + x4 * wb1.x + x5 * wb1.y + x6 * wb1.z + x7 * wb1.w;
                    a2 += x0 * wa2.x + x1 * wa2.y + x2v * wa2.z + x3 * wa2.w
                        + x4 * wb2.x + x5 * wb2.y + x6 * wb2.z + x7 * wb2.w;
                }
            }
        }
    }
    // reduce over the 4 ci-quarters (lanes p^1, p^2)
    a0 += __shfl_xor(a0, 1); a0 += __shfl_xor(a0, 2);
    a1 += __shfl_xor(a1, 1); a1 += __shfl_xor(a1, 2);
    a2 += __shfl_xor(a2, 1); a2 += __shfl_xor(a2, 2);
    float av = (p == 0) ? a0 : ((p == 1) ? a1 : a2);
    if (p < 3)
        out[(size_t)(b * 3 + p) * 76800 + r] = av + cb[p];
}

// ---------------------------------------------------------------------------
extern "C" void kernel_launch(void* const* d_in, const int* in_sizes, int n_in,
                              void* d_out, int out_size, void* d_ws, size_t ws_size,
                              hipStream_t stream)
{
    (void)in_sizes; (void)n_in; (void)out_size;

    const float* Im  = (const float*)d_in[0];
    const float* If  = (const float*)d_in[1];
    const float* g1q = (const float*)d_in[2];
    const float* b1q = (const float*)d_in[3];
    const float* g1k = (const float*)d_in[4];
    const float* b1k = (const float*)d_in[5];
    const float* wq  = (const float*)d_in[6];
    const float* bq  = (const float*)d_in[7];
    const float* wkv = (const float*)d_in[8];
    const float* bkv = (const float*)d_in[9];
    const float* wpj = (const float*)d_in[10];
    const float* bpj = (const float*)d_in[11];
    const float* rb  = (const float*)d_in[12];
    const float* g2  = (const float*)d_in[13];
    const float* b2  = (const float*)d_in[14];
    const float* w1  = (const float*)d_in[15];
    const float* b1  = (const float*)d_in[16];
    const float* w2  = (const float*)d_in[17];
    const float* b2v = (const float*)d_in[18];
    const float* cw  = (const float*)d_in[19];
    const float* cb  = (const float*)d_in[20];
    float* out = (float*)d_out;

    size_t U = (size_t)NTOK * 96;
    if (ws_size < 4 * U * sizeof(float)) return;
    float* ws = (float*)d_ws;
    bf16_t* xlnb = (bf16_t*)ws;                        // U bf16 (-> xc later)
    bf16_t* ylnb = (bf16_t*)(ws + U / 2);              // U bf16
    bf16_t* qb   = (bf16_t*)(ws + U);                  // U bf16
    bf16_t* kb   = (bf16_t*)(ws + 3 * U / 2);          // U bf16
    bf16_t* vT   = (bf16_t*)(ws + 2 * U);              // 1024*96*160 bf16
    float*  wtail = ws + 2 * U + (1024 * 96 * 160) / 2;
    bf16_t* wqT  = (bf16_t*)wtail;                     // 9216
    bf16_t* wkvT = wqT + 9216;                         // 18432
    bf16_t* w1T  = wkvT + 18432;                       // 36864
    bf16_t* w2T  = w1T + 36864;                        // 36864
    bf16_t* wpjT = w2T + 36864;                        // 9216
    float*  bias_mat = (float*)(wpjT + 9216 + 2);      // 25600 fp32
    float*  cwT  = bias_mat + 25600;                   // 7776 fp32
    float*  x2f  = ws + 3 * U;                         // U fp32
    bf16_t* xc   = (bf16_t*)ws;                        // U bf16, spatial order

    k_prep_weights<<<144, 256, 0, stream>>>(wq, wkv, w1, w2, wpj, rb, cw,
                                            wqT, wkvT, w1T, w2T, wpjT,
                                            bias_mat, cwT);
    k_ln_transpose<<<3840, 256, 0, stream>>>(Im, If, g1q, b1q, g1k, b1k,
                                             xlnb, ylnb, x2f);
    size_t shm_q  = (size_t)(64 * 104 + 96 * 104) * sizeof(bf16_t);   // 33280
    size_t shm_kv = (size_t)(64 * 104 + 192 * 104) * sizeof(bf16_t);  // 53248
    k_proj_mfma<<<2400, 256, shm_q, stream>>>(xlnb, wqT, bq, 96, qb, nullptr);
    k_proj_mfma<<<2400, 256, shm_kv, stream>>>(ylnb, wkvT, bkv, 192, kb, vT);
    k_attn_mfma<<<1024, 384, 0, stream>>>(qb, kb, vT, wpjT, bias_mat, bpj, x2f);
    k_mlp_mfma<<<1200, 256, 0, stream>>>(x2f, g2, b2, w1T, b1, w2T, b2v, xc);
    k_conv<<<2400, 256, 0, stream>>>(xc, cwT, cb, out);
}

// Round 5
// 535.912 us; speedup vs baseline: 1.3017x; 1.0851x over previous
//
#include <hip/hip_runtime.h>
#include <math.h>

// ---------------------------------------------------------------------------
// Swin-3D cross-attention block. Round 11:
//  - k_attn v2: waveized. One wave = one (window, row-tile) task, no K LDS
//    staging (28.8 KB K fits L1, shared by same-window waves), no barriers,
//    LDS = 21 KB wave-private P/O scratch only. Writes attn output to bf16
//    aob buffer instead of fp32 x2 RMW (kills 118 MB of HBM traffic).
//  - k_mlp: reconstructs x2 = x2s + aob in LN phase and epilogue.
//  - buffers: aob reuses xlnb region (dead after proj_q); xc moves to ylnb
//    region (dead after proj_kv).
// Token order = window-partitioned:
//   win = ((b*8 + d/5)*8 + h/6)*8 + w/5 ; t = ((d%5)*6 + h%6)*5 + w%5
// ---------------------------------------------------------------------------

static constexpr int NTOK = 153600;
static constexpr float SCALE = 0.10206207261596575f; // 96^-0.5

typedef __bf16 bf16_t;
typedef __bf16 bf16x8 __attribute__((ext_vector_type(8)));
typedef float f32x4 __attribute__((ext_vector_type(4)));

__device__ __forceinline__ int tok_index(int b, int d, int h, int w) {
    int d0 = d / 5, wd = d % 5;
    int h0 = h / 6, wh = h % 6;
    int w0 = w / 5, ww = w % 5;
    int win = ((b * 8 + d0) * 8 + h0) * 8 + w0;
    return win * 150 + (wd * 6 + wh) * 5 + ww;
}

__device__ __forceinline__ float gelu_f(float u) {
    float u2 = u * u;
    float arg = u * fmaf(0.0713549f, u2, 1.5957691f);
    float e = __expf(arg);
    float r = __builtin_amdgcn_rcpf(e + 1.f);
    return fmaf(-u, r, u);
}

// ---------------------------------------------------------------------------
// K0: weight convert/transpose bf16 [n][k]; fp32 bias matrix [160][160];
// conv weights re-laid to cwT[kk][oc][ci] (ci-contiguous for float4 reads).
// ---------------------------------------------------------------------------
__global__ __launch_bounds__(256) void k_prep_weights(
    const float* __restrict__ wq, const float* __restrict__ wkv,
    const float* __restrict__ w1, const float* __restrict__ w2,
    const float* __restrict__ wproj, const float* __restrict__ relb,
    const float* __restrict__ cw,
    bf16_t* wqT, bf16_t* wkvT, bf16_t* w1T, bf16_t* w2T, bf16_t* wpjT,
    float* bias_mat, float* cwT)
{
    int i = blockIdx.x * 256 + threadIdx.x;
    if (i < 9216)  wqT[i]  = (bf16_t)wq[(i % 96) * 96 + i / 96];
    if (i < 18432) wkvT[i] = (bf16_t)wkv[(i % 96) * 192 + i / 96];
    if (i < 36864) w1T[i]  = (bf16_t)w1[(i % 96) * 384 + i / 96];
    if (i < 36864) w2T[i]  = (bf16_t)w2[(i % 384) * 96 + i / 384];
    if (i < 9216)  wpjT[i] = (bf16_t)wproj[(i % 96) * 96 + i / 96];
    if (i < 25600) {
        int row = i / 160, col = i % 160;
        float v;
        if (col >= 150) v = -1e30f;
        else if (row >= 150) v = 0.f;
        else {
            int wd1 = row / 30, rh1 = row % 30, wh1 = rh1 / 5, ww1 = rh1 % 5;
            int wd2 = col / 30, rh2 = col % 30, wh2 = rh2 / 5, ww2 = rh2 % 5;
            int idx = (wd1 - wd2 + 4) * 99 + (wh1 - wh2 + 5) * 9 + (ww1 - ww2 + 4);
            v = relb[idx];
        }
        bias_mat[i] = v;
    }
    if (i < 7776) {
        int kk = i / 288, rem = i % 288;
        int oc = rem / 96, ci = rem % 96;
        cwT[i] = cw[oc * 2592 + ci * 27 + kk];
    }
}

// ---------------------------------------------------------------------------
// K1: transpose->token order + LayerNorm (bf16 out) + fp32 Im shortcut to x2.
// grid = 3840, 256 threads.
// ---------------------------------------------------------------------------
__global__ __launch_bounds__(256) void k_ln_transpose(
    const float* __restrict__ Im, const float* __restrict__ If,
    const float* __restrict__ g1q, const float* __restrict__ b1q,
    const float* __restrict__ g1k, const float* __restrict__ b1k,
    bf16_t* __restrict__ xln, bf16_t* __restrict__ yln,
    float* __restrict__ x2s)
{
    __shared__ float tile[40 * 97];
    __shared__ float mean_s[40], rstd_s[40];
    int blk = blockIdx.x;
    int b = blk / (40 * 48);
    int rem = blk % (40 * 48);
    int d = rem / 48, h = rem % 48;
    int tid = threadIdx.x;

    for (int pass = 0; pass < 2; ++pass) {
        const float* src = pass ? If : Im;
        const float* gg = pass ? g1k : g1q;
        const float* bb = pass ? b1k : b1q;
        bf16_t* dst = pass ? yln : xln;

        for (int i = tid; i < 96 * 40; i += 256) {
            int c = i / 40, w = i % 40;
            tile[w * 97 + c] = src[(size_t)(b * 96 + c) * 76800 + d * 1920 + h * 40 + w];
        }
        __syncthreads();
        if (tid < 40) {
            float s = 0.f, s2 = 0.f;
            for (int c = 0; c < 96; ++c) {
                float v = tile[tid * 97 + c];
                s += v; s2 += v * v;
            }
            float m = s * (1.f / 96.f);
            float var = s2 * (1.f / 96.f) - m * m;
            mean_s[tid] = m;
            rstd_s[tid] = rsqrtf(var + 1e-5f);
        }
        __syncthreads();
        for (int i = tid; i < 40 * 96; i += 256) {
            int w = i / 96, c = i % 96;
            int tok = tok_index(b, d, h, w);
            float raw = tile[w * 97 + c];
            float v = (raw - mean_s[w]) * rstd_s[w] * gg[c] + bb[c];
            dst[(size_t)tok * 96 + c] = (bf16_t)v;
            if (pass == 0) x2s[(size_t)tok * 96 + c] = raw;   // shortcut
        }
        __syncthreads();
    }
}

// ---------------------------------------------------------------------------
// K2: MFMA projection. WT is [N][96] bf16, staged once per block into LDS
// ([N][104] padded) so B-frags come from LDS, not per-MFMA global loads.
// N=96 -> qb only. N=192 -> n<96 writes kb [t][c]; n>=96 writes vT.
// grid = 2400 (64 tokens/block), 256 threads = 4 waves.
// dynamic LDS = (64*104 + N*104)*2 B.
// ---------------------------------------------------------------------------
__global__ __launch_bounds__(256) void k_proj_mfma(
    const bf16_t* __restrict__ X, const bf16_t* __restrict__ WT,
    const float* __restrict__ bias, int N,
    bf16_t* __restrict__ outA, bf16_t* __restrict__ vT)
{
    extern __shared__ bf16_t sm[];
    bf16_t* xs  = sm;             // [64][104]
    bf16_t* wsh = sm + 64 * 104;  // [N][104]
    int tid = threadIdx.x;
    int t0 = blockIdx.x * 64;

    const uint4* xg = (const uint4*)(X + (size_t)t0 * 96);
    uint4* xsv = (uint4*)xs;
    for (int i = tid; i < 768; i += 256) {
        int row = i / 12, c16 = i % 12;
        xsv[row * 13 + c16] = xg[i];
    }
    const uint4* wg = (const uint4*)WT;
    uint4* wsv = (uint4*)wsh;
    for (int i = tid; i < N * 12; i += 256) {
        int row = i / 12, c16 = i % 12;
        wsv[row * 13 + c16] = wg[i];
    }
    __syncthreads();

    int w = tid >> 6, l = tid & 63;
    int lm = l & 15, lk = (l >> 4) * 8;
    int m0 = w * 16;
    bf16x8 a[3];
#pragma unroll
    for (int kk = 0; kk < 3; ++kk)
        a[kk] = *(const bf16x8*)(xs + (m0 + lm) * 104 + kk * 32 + lk);

    int trow[4], twin[4], tm[4];
#pragma unroll
    for (int r = 0; r < 4; ++r) {
        int t = t0 + m0 + (l >> 4) * 4 + r;
        trow[r] = t; twin[r] = t / 150; tm[r] = t - twin[r] * 150;
    }

    int ntiles = N >> 4;
    for (int ti = 0; ti < ntiles; ++ti) {
        int n0 = ti * 16;
        f32x4 c = {0.f, 0.f, 0.f, 0.f};
        const bf16_t* wp = wsh + (size_t)(n0 + lm) * 104 + lk;
        c = __builtin_amdgcn_mfma_f32_16x16x32_bf16(a[0], *(const bf16x8*)(wp), c, 0, 0, 0);
        c = __builtin_amdgcn_mfma_f32_16x16x32_bf16(a[1], *(const bf16x8*)(wp + 32), c, 0, 0, 0);
        c = __builtin_amdgcn_mfma_f32_16x16x32_bf16(a[2], *(const bf16x8*)(wp + 64), c, 0, 0, 0);
        int n = n0 + lm;
        float bs = bias[n];
        if (n < 96) {
#pragma unroll
            for (int r = 0; r < 4; ++r)
                outA[(size_t)trow[r] * 96 + n] = (bf16_t)(c[r] + bs);
        } else {
            int cc = n - 96;
#pragma unroll
            for (int r = 0; r < 4; ++r)
                vT[((size_t)twin[r] * 96 + cc) * 160 + tm[r]] = (bf16_t)(c[r] + bs);
        }
    }
}

// ---------------------------------------------------------------------------
// K34 v2: waveized MFMA attention. One wave = one (window, row-tile) task,
// 10240 tasks, 4 waves/block, grid 2560. No barriers, no K staging (K is
// L1/L2-hot: 28.8 KB/window shared by its 10 waves). P/O transpose through
// wave-private LDS scratch [16][164]. K rows >=150 clamp-loaded (masked by
// bias -1e30). Output: aob[t][c] = O @ wprojT + bproj (bf16), no x2 RMW.
// ---------------------------------------------------------------------------
__global__ __launch_bounds__(256, 4) void k_attn_mfma(
    const bf16_t* __restrict__ qb, const bf16_t* __restrict__ kb,
    const bf16_t* __restrict__ vT, const bf16_t* __restrict__ wpjT,
    const float* __restrict__ bias_mat, const float* __restrict__ bproj,
    bf16_t* __restrict__ aob)
{
    __shared__ __align__(16) bf16_t pls_all[4 * 16 * 164]; // 20992 B
    int tid = threadIdx.x;
    int wv = tid >> 6, l = tid & 63;
    int task = blockIdx.x * 4 + wv;
    int win = task / 10, ti = task - win * 10;
    int lm = l & 15, lq = l >> 4, lk8 = lq * 8;
    size_t wbase = (size_t)win * 150 * 96;
    size_t vbase = (size_t)win * 96 * 160;
    bf16_t* pls = pls_all + wv * 16 * 164;
    int r0 = ti * 16;

    // ---- Q A-frags from global (rows >=150 read harmless garbage; masked) --
    bf16x8 aq[3];
#pragma unroll
    for (int kk = 0; kk < 3; ++kk)
        aq[kk] = *(const bf16x8*)(qb + wbase + (size_t)(r0 + lm) * 96 + kk * 32 + lk8);

    // ---- S = Q K^T (K B-frags from global, L1-hot; clamp rows >=150) ----
    f32x4 s[10];
#pragma unroll
    for (int nt = 0; nt < 10; ++nt) {
        int krow = nt * 16 + lm;
        if (krow > 149) krow = 149;   // finite duplicate, masked by bias
        f32x4 acc = {0.f, 0.f, 0.f, 0.f};
        const bf16_t* kp = kb + wbase + (size_t)krow * 96 + lk8;
        acc = __builtin_amdgcn_mfma_f32_16x16x32_bf16(aq[0], *(const bf16x8*)(kp), acc, 0, 0, 0);
        acc = __builtin_amdgcn_mfma_f32_16x16x32_bf16(aq[1], *(const bf16x8*)(kp + 32), acc, 0, 0, 0);
        acc = __builtin_amdgcn_mfma_f32_16x16x32_bf16(aq[2], *(const bf16x8*)(kp + 64), acc, 0, 0, 0);
        s[nt] = acc;
    }

    // ---- softmax (bias+mask folded into bias_mat) ----
#pragma unroll
    for (int r = 0; r < 4; ++r) {
        int grow = r0 + lq * 4 + r;
        float rowmax = -3.0e38f;
#pragma unroll
        for (int nt = 0; nt < 10; ++nt) {
            float bv = bias_mat[grow * 160 + nt * 16 + lm];
            float v = fmaf(s[nt][r], SCALE, bv);
            s[nt][r] = v;
            rowmax = fmaxf(rowmax, v);
        }
        rowmax = fmaxf(rowmax, __shfl_xor(rowmax, 1));
        rowmax = fmaxf(rowmax, __shfl_xor(rowmax, 2));
        rowmax = fmaxf(rowmax, __shfl_xor(rowmax, 4));
        rowmax = fmaxf(rowmax, __shfl_xor(rowmax, 8));
        float ssum = 0.f;
#pragma unroll
        for (int nt = 0; nt < 10; ++nt) {
            float e = __expf(s[nt][r] - rowmax);
            s[nt][r] = e;
            ssum += e;
        }
        ssum += __shfl_xor(ssum, 1);
        ssum += __shfl_xor(ssum, 2);
        ssum += __shfl_xor(ssum, 4);
        ssum += __shfl_xor(ssum, 8);
        float inv = 1.f / ssum;
        int lrow = lq * 4 + r;
#pragma unroll
        for (int nt = 0; nt < 10; ++nt)
            pls[lrow * 164 + nt * 16 + lm] = (bf16_t)(s[nt][r] * inv);
    }
    // wave-private LDS: no barrier needed (lgkmcnt orders within wave)

    // ---- O = P @ V (P A-frags from LDS, V B-frags from global, L2-hot) ----
    f32x4 o[6];
#pragma unroll
    for (int ct = 0; ct < 6; ++ct) o[ct] = (f32x4){0.f, 0.f, 0.f, 0.f};
#pragma unroll
    for (int kf = 0; kf < 5; ++kf) {
        bf16x8 ap = *(const bf16x8*)(pls + lm * 164 + kf * 32 + lk8);
#pragma unroll
        for (int ct = 0; ct < 6; ++ct) {
            const bf16_t* vp = vT + vbase + (size_t)(ct * 16 + lm) * 160 + kf * 32 + lk8;
            o[ct] = __builtin_amdgcn_mfma_f32_16x16x32_bf16(ap, *(const bf16x8*)(vp), o[ct], 0, 0, 0);
        }
    }

    // ---- O -> LDS (A-layout staging), reuse pls as [16][104] ----
#pragma unroll
    for (int ct = 0; ct < 6; ++ct)
#pragma unroll
        for (int r = 0; r < 4; ++r)
            pls[(lq * 4 + r) * 104 + ct * 16 + lm] = (bf16_t)o[ct][r];

    // ---- aob = O @ wprojT + bproj (bf16) ----
    bf16x8 ao[3];
#pragma unroll
    for (int kk = 0; kk < 3; ++kk)
        ao[kk] = *(const bf16x8*)(pls + lm * 104 + kk * 32 + lk8);
    f32x4 pj[6];
#pragma unroll
    for (int ct = 0; ct < 6; ++ct) {
        f32x4 acc = {0.f, 0.f, 0.f, 0.f};
        const bf16_t* wp = wpjT + (size_t)(ct * 16 + lm) * 96 + lk8;
        acc = __builtin_amdgcn_mfma_f32_16x16x32_bf16(ao[0], *(const bf16x8*)(wp), acc, 0, 0, 0);
        acc = __builtin_amdgcn_mfma_f32_16x16x32_bf16(ao[1], *(const bf16x8*)(wp + 32), acc, 0, 0, 0);
        acc = __builtin_amdgcn_mfma_f32_16x16x32_bf16(ao[2], *(const bf16x8*)(wp + 64), acc, 0, 0, 0);
        pj[ct] = acc;
    }
#pragma unroll
    for (int r = 0; r < 4; ++r) {
        int gr = r0 + lq * 4 + r;
        if (gr < 150) {
            size_t t = (size_t)win * 150 + gr;
#pragma unroll
            for (int ct = 0; ct < 6; ++ct) {
                int c = ct * 16 + lm;
                aob[t * 96 + c] = (bf16_t)(pj[ct][r] + bproj[c]);
            }
        }
    }
}

// ---------------------------------------------------------------------------
// K5: MFMA MLP v4. x2 reconstructed as x2s + aob (bf16 attn-out) in both LN
// phase and epilogue (re-reads are L3-hot). One wave = 32 tokens (2 M-tiles),
// weight B-frags shared across M-tiles, 12 independent acc chains.
// LDS = 53248 B -> 3 blk/CU. grid = 1200 (128 tokens), 256 threads = 4 waves.
// ---------------------------------------------------------------------------
__global__ __launch_bounds__(256, 3) void k_mlp_mfma(
    const float* __restrict__ x2,
    const bf16_t* __restrict__ aob,
    const float* __restrict__ g2, const float* __restrict__ b2,
    const bf16_t* __restrict__ w1T, const float* __restrict__ b1,
    const bf16_t* __restrict__ w2T, const float* __restrict__ b2v,
    bf16_t* __restrict__ xc)
{
    __shared__ __align__(16) bf16_t xs[128 * 104];     // 26624 B
    __shared__ __align__(16) bf16_t hs[4 * 32 * 104];  // 26624 B

    int tid = threadIdx.x;
    int t0 = blockIdx.x * 128;

    // ---- register LayerNorm: thread = (token t, half p); x2 = x2s + aob ----
    {
        int t = tid >> 1, p = tid & 1;
        float xr[48];
        const float4* xg = (const float4*)(x2 + (size_t)(t0 + t) * 96 + p * 48);
        const bf16x8* ag = (const bf16x8*)(aob + (size_t)(t0 + t) * 96 + p * 48);
#pragma unroll
        for (int j4 = 0; j4 < 12; ++j4) {
            float4 v = xg[j4];
            xr[j4 * 4 + 0] = v.x; xr[j4 * 4 + 1] = v.y;
            xr[j4 * 4 + 2] = v.z; xr[j4 * 4 + 3] = v.w;
        }
#pragma unroll
        for (int j8 = 0; j8 < 6; ++j8) {
            bf16x8 av = ag[j8];
#pragma unroll
            for (int e = 0; e < 8; ++e)
                xr[j8 * 8 + e] += (float)av[e];
        }
        float s = 0.f, s2 = 0.f;
#pragma unroll
        for (int j = 0; j < 48; ++j) { s += xr[j]; s2 += xr[j] * xr[j]; }
        s += __shfl_xor(s, 1);
        s2 += __shfl_xor(s2, 1);
        float m = s * (1.f / 96.f);
        float var = s2 * (1.f / 96.f) - m * m;
        float rstd = rsqrtf(var + 1e-5f);

        const float4* gg = (const float4*)(g2 + p * 48);
        const float4* bb = (const float4*)(b2 + p * 48);
        bf16_t tmp[48];
#pragma unroll
        for (int j4 = 0; j4 < 12; ++j4) {
            float4 g = gg[j4], bv = bb[j4];
            tmp[j4 * 4 + 0] = (bf16_t)((xr[j4 * 4 + 0] - m) * rstd * g.x + bv.x);
            tmp[j4 * 4 + 1] = (bf16_t)((xr[j4 * 4 + 1] - m) * rstd * g.y + bv.y);
            tmp[j4 * 4 + 2] = (bf16_t)((xr[j4 * 4 + 2] - m) * rstd * g.z + bv.z);
            tmp[j4 * 4 + 3] = (bf16_t)((xr[j4 * 4 + 3] - m) * rstd * g.w + bv.w);
        }
        uint4* dst = (uint4*)(xs + t * 104 + p * 48);   // 96B per half
        const uint4* src = (const uint4*)tmp;
#pragma unroll
        for (int j = 0; j < 6; ++j) dst[j] = src[j];
    }
    // NO __syncthreads(): token rows [32w,32w+32) of xs are written by tids
    // [64w,64w+64) = wave w itself; in-wave DS ordering suffices.

    int w = tid >> 6, l = tid & 63;
    int lm = l & 15, lq = l >> 4, lk = lq * 8;
    int m0 = w * 32;
    bf16_t* hw = hs + w * 32 * 104;

    bf16x8 a[2][3];
#pragma unroll
    for (int mt = 0; mt < 2; ++mt)
#pragma unroll
        for (int kk = 0; kk < 3; ++kk)
            a[mt][kk] = *(const bf16x8*)(xs + (m0 + mt * 16 + lm) * 104 + kk * 32 + lk);

    f32x4 acc2[2][6];
#pragma unroll
    for (int mt = 0; mt < 2; ++mt)
#pragma unroll
        for (int i = 0; i < 6; ++i) acc2[mt][i] = (f32x4){0.f, 0.f, 0.f, 0.f};

#pragma unroll
    for (int cc = 0; cc < 4; ++cc) {
        // ---- stage1: h = gelu(x @ w1_cc + b1); weight triple shared by 2 M ----
#pragma unroll
        for (int ti = 0; ti < 6; ++ti) {
            int n = cc * 96 + ti * 16 + lm;
            const bf16_t* wp = w1T + (size_t)n * 96 + lk;
            bf16x8 w0 = *(const bf16x8*)(wp);
            bf16x8 w1v = *(const bf16x8*)(wp + 32);
            bf16x8 w2v = *(const bf16x8*)(wp + 64);
            float bs = b1[n];
#pragma unroll
            for (int mt = 0; mt < 2; ++mt) {
                f32x4 c1 = {0.f, 0.f, 0.f, 0.f};
                c1 = __builtin_amdgcn_mfma_f32_16x16x32_bf16(a[mt][0], w0, c1, 0, 0, 0);
                c1 = __builtin_amdgcn_mfma_f32_16x16x32_bf16(a[mt][1], w1v, c1, 0, 0, 0);
                c1 = __builtin_amdgcn_mfma_f32_16x16x32_bf16(a[mt][2], w2v, c1, 0, 0, 0);
#pragma unroll
                for (int r = 0; r < 4; ++r)
                    hw[(mt * 16 + lq * 4 + r) * 104 + ti * 16 + lm] =
                        (bf16_t)gelu_f(c1[r] + bs);
            }
        }

        // ---- stage2: acc2 += h_cc @ w2_cc ----
        bf16x8 ha[2][3];
#pragma unroll
        for (int mt = 0; mt < 2; ++mt)
#pragma unroll
            for (int kk = 0; kk < 3; ++kk)
                ha[mt][kk] = *(const bf16x8*)(hw + (mt * 16 + lm) * 104 + kk * 32 + lk);
#pragma unroll
        for (int ti = 0; ti < 6; ++ti) {
            const bf16_t* wp = w2T + (size_t)(ti * 16 + lm) * 384 + cc * 96 + lk;
            bf16x8 v0 = *(const bf16x8*)(wp);
            bf16x8 v1 = *(const bf16x8*)(wp + 32);
            bf16x8 v2 = *(const bf16x8*)(wp + 64);
#pragma unroll
            for (int mt = 0; mt < 2; ++mt) {
                acc2[mt][ti] = __builtin_amdgcn_mfma_f32_16x16x32_bf16(ha[mt][0], v0, acc2[mt][ti], 0, 0, 0);
                acc2[mt][ti] = __builtin_amdgcn_mfma_f32_16x16x32_bf16(ha[mt][1], v1, acc2[mt][ti], 0, 0, 0);
                acc2[mt][ti] = __builtin_amdgcn_mfma_f32_16x16x32_bf16(ha[mt][2], v2, acc2[mt][ti], 0, 0, 0);
            }
        }
    }

    // epilogue: residual (x2s + aob) + bias; write bf16 in spatial order
#pragma unroll
    for (int mt = 0; mt < 2; ++mt) {
        int srow[4];
#pragma unroll
        for (int r = 0; r < 4; ++r) {
            int t = t0 + m0 + mt * 16 + lq * 4 + r;
            int win = t / 150, nn = t - win * 150;
            int b = win >> 9, d0 = (win >> 6) & 7, h0 = (win >> 3) & 7, w0 = win & 7;
            int wd = nn / 30, rem = nn % 30, wh = rem / 5, ww = rem % 5;
            srow[r] = ((b * 40 + d0 * 5 + wd) * 48 + h0 * 6 + wh) * 40 + w0 * 5 + ww;
        }
#pragma unroll
        for (int ti = 0; ti < 6; ++ti) {
            int n = ti * 16 + lm;
            float bs = b2v[n];
#pragma unroll
            for (int r = 0; r < 4; ++r) {
                int t = t0 + m0 + mt * 16 + lq * 4 + r;
                size_t o = (size_t)t * 96 + n;
                float base = x2[o] + (float)aob[o];
                xc[(size_t)srow[r] * 96 + n] = (bf16_t)(base + acc2[mt][ti][r] + bs);
            }
        }
    }
}

// ---------------------------------------------------------------------------
// K6: 3x3x3 conv (96 -> 3), zero pad. Input xc: bf16, spatial (b,d,h,w,c).
// v2: 4 lanes per point, 24 ci each (3 bf16x8 chunks); shfl_xor reduce over
// lanes 1,2; lane p<3 writes output plane p. grid = 2400.
// ---------------------------------------------------------------------------
__global__ __launch_bounds__(256) void k_conv(
    const bf16_t* __restrict__ xc, const float* __restrict__ cwT,
    const float* __restrict__ cb, float* __restrict__ out)
{
    __shared__ float wl[7776];   // [kk][oc][ci]
    int tid = threadIdx.x;
    for (int i = tid; i < 7776; i += 256) wl[i] = cwT[i];
    __syncthreads();

    int gid = blockIdx.x * 256 + tid;
    int s = gid >> 2, p = gid & 3;          // point, ci-quarter
    int b = s / 76800, r = s % 76800;
    int d = r / 1920, h = (r / 40) % 48, w = r % 40;
    float a0 = 0.f, a1 = 0.f, a2 = 0.f;

    for (int dd = 0; dd < 3; ++dd) {
        int d2 = d + dd - 1;
        if ((unsigned)d2 >= 40u) continue;
        for (int hh = 0; hh < 3; ++hh) {
            int h2 = h + hh - 1;
            if ((unsigned)h2 >= 48u) continue;
            for (int ww = 0; ww < 3; ++ww) {
                int w2 = w + ww - 1;
                if ((unsigned)w2 >= 40u) continue;
                int kk = (dd * 3 + hh) * 3 + ww;
                const bf16x8* xp = (const bf16x8*)
                    (xc + ((size_t)((b * 40 + d2) * 48 + h2) * 40 + w2) * 96 + p * 24);
                const float* wk = wl + kk * 288 + p * 24;
#pragma unroll
                for (int c8 = 0; c8 < 3; ++c8) {
                    bf16x8 xv = xp[c8];
                    float x0 = (float)xv[0], x1 = (float)xv[1];
                    float x2v = (float)xv[2], x3 = (float)xv[3];
                    float x4 = (float)xv[4], x5 = (float)xv[5];
                    float x6 = (float)xv[6], x7 = (float)xv[7];
                    float4 wa0 = *(const float4*)(wk + c8 * 8);
                    float4 wb0 = *(const float4*)(wk + c8 * 8 + 4);
                    float4 wa1 = *(const float4*)(wk + 96 + c8 * 8);
                    float4 wb1 = *(const float4*)(wk + 96 + c8 * 8 + 4);
                    float4 wa2 = *(const float4*)(wk + 192 + c8 * 8);
                    float4 wb2 = *(const float4*)(wk + 192 + c8 * 8 + 4);
                    a0 += x0 * wa0.x + x1 * wa0.y + x2v * wa0.z + x3 * wa0.w
                        + x4 * wb0.x + x5 * wb0.y + x6 * wb0.z + x7 * wb0.w;
                    a1 += x0 * wa1.x + x1 * wa1.y + x2v * wa1.z + x3 * wa1.w
                        + x4 * wb1.x + x5 * wb1.y + x6 * wb1.z + x7 * wb1.w;
                    a2 += x0 * wa2.x + x1 * wa2.y + x2v * wa2.z + x3 * wa2.w
                        + x4 * wb2.x + x5 * wb2.y + x6 * wb2.z + x7 * wb2.w;
                }
            }
        }
    }
    // reduce over the 4 ci-quarters (lanes p^1, p^2)
    a0 += __shfl_xor(a0, 1); a0 += __shfl_xor(a0, 2);
    a1 += __shfl_xor(a1, 1); a1 += __shfl_xor(a1, 2);
    a2 += __shfl_xor(a2, 1); a2 += __shfl_xor(a2, 2);
    float av = (p == 0) ? a0 : ((p == 1) ? a1 : a2);
    if (p < 3)
        out[(size_t)(b * 3 + p) * 76800 + r] = av + cb[p];
}

// ---------------------------------------------------------------------------
extern "C" void kernel_launch(void* const* d_in, const int* in_sizes, int n_in,
                              void* d_out, int out_size, void* d_ws, size_t ws_size,
                              hipStream_t stream)
{
    (void)in_sizes; (void)n_in; (void)out_size;

    const float* Im  = (const float*)d_in[0];
    const float* If  = (const float*)d_in[1];
    const float* g1q = (const float*)d_in[2];
    const float* b1q = (const float*)d_in[3];
    const float* g1k = (const float*)d_in[4];
    const float* b1k = (const float*)d_in[5];
    const float* wq  = (const float*)d_in[6];
    const float* bq  = (const float*)d_in[7];
    const float* wkv = (const float*)d_in[8];
    const float* bkv = (const float*)d_in[9];
    const float* wpj = (const float*)d_in[10];
    const float* bpj = (const float*)d_in[11];
    const float* rb  = (const float*)d_in[12];
    const float* g2  = (const float*)d_in[13];
    const float* b2  = (const float*)d_in[14];
    const float* w1  = (const float*)d_in[15];
    const float* b1  = (const float*)d_in[16];
    const float* w2  = (const float*)d_in[17];
    const float* b2v = (const float*)d_in[18];
    const float* cw  = (const float*)d_in[19];
    const float* cb  = (const float*)d_in[20];
    float* out = (float*)d_out;

    size_t U = (size_t)NTOK * 96;
    if (ws_size < 4 * U * sizeof(float)) return;
    float* ws = (float*)d_ws;
    bf16_t* xlnb = (bf16_t*)ws;                        // U bf16 (-> aob later)
    bf16_t* ylnb = (bf16_t*)(ws + U / 2);              // U bf16 (-> xc later)
    bf16_t* qb   = (bf16_t*)(ws + U);                  // U bf16
    bf16_t* kb   = (bf16_t*)(ws + 3 * U / 2);          // U bf16
    bf16_t* vT   = (bf16_t*)(ws + 2 * U);              // 1024*96*160 bf16
    float*  wtail = ws + 2 * U + (1024 * 96 * 160) / 2;
    bf16_t* wqT  = (bf16_t*)wtail;                     // 9216
    bf16_t* wkvT = wqT + 9216;                         // 18432
    bf16_t* w1T  = wkvT + 18432;                       // 36864
    bf16_t* w2T  = w1T + 36864;                        // 36864
    bf16_t* wpjT = w2T + 36864;                        // 9216
    float*  bias_mat = (float*)(wpjT + 9216 + 2);      // 25600 fp32
    float*  cwT  = bias_mat + 25600;                   // 7776 fp32
    float*  x2f  = ws + 3 * U;                         // U fp32 (x2s shortcut)
    bf16_t* aob  = (bf16_t*)ws;                        // U bf16 (attn out)
    bf16_t* xc   = (bf16_t*)(ws + U / 2);              // U bf16, spatial order

    k_prep_weights<<<144, 256, 0, stream>>>(wq, wkv, w1, w2, wpj, rb, cw,
                                            wqT, wkvT, w1T, w2T, wpjT,
                                            bias_mat, cwT);
    k_ln_transpose<<<3840, 256, 0, stream>>>(Im, If, g1q, b1q, g1k, b1k,
                                             xlnb, ylnb, x2f);
    size_t shm_q  = (size_t)(64 * 104 + 96 * 104) * sizeof(bf16_t);   // 33280
    size_t shm_kv = (size_t)(64 * 104 + 192 * 104) * sizeof(bf16_t);  // 53248
    k_proj_mfma<<<2400, 256, shm_q, stream>>>(xlnb, wqT, bq, 96, qb, nullptr);
    k_proj_mfma<<<2400, 256, shm_kv, stream>>>(ylnb, wkvT, bkv, 192, kb, vT);
    // xlnb/ylnb dead from here; aob reuses xlnb region, xc reuses ylnb region
    k_attn_mfma<<<2560, 256, 0, stream>>>(qb, kb, vT, wpjT, bias_mat, bpj, aob);
    k_mlp_mfma<<<1200, 256, 0, stream>>>(x2f, aob, g2, b2, w1T, b1, w2T, b2v, xc);
    k_conv<<<2400, 256, 0, stream>>>(xc, cwT, cb, out);
}